// Round 13
// baseline (412.680 us; speedup 1.0000x reference)
//
#include <hip/hip_runtime.h>
#include <cstdint>
#include <cstddef>

#define DEV static __device__ __forceinline__

typedef __bf16 bf16x8 __attribute__((ext_vector_type(8)));
typedef float f32x4 __attribute__((ext_vector_type(4)));
typedef unsigned short u16x8 __attribute__((ext_vector_type(8)));
typedef unsigned short u16;

DEV u16 f2bf(float f) { __bf16 b = (__bf16)f; return __builtin_bit_cast(u16, b); }

DEV void async_cp16(const void* g, void* l) {
    __builtin_amdgcn_global_load_lds(
        (const __attribute__((address_space(1))) void*)g,
        (__attribute__((address_space(3))) void*)l, 16, 0, 0);
}

DEV void wait_vm6() { asm volatile("s_waitcnt vmcnt(6)" ::: "memory"); }
DEV void wait_vm4() { asm volatile("s_waitcnt vmcnt(4)" ::: "memory"); }
DEV void wait_vm0() { asm volatile("s_waitcnt vmcnt(0)" ::: "memory"); }

// gelu with module's custom 0.04715 constant; overflow-safe tanh
DEV float gelu_fn(float x) {
    const float c = 0.7978845608028654f; // sqrt(2/pi)
    float t = c * (x + 0.04715f * x * x * x);
    float e = __expf(2.f * t);
    float th = 1.f - 2.f / (e + 1.f); // tanh(t), safe at +-inf
    return 0.5f * x * (1.f + th);
}

// ------------- fused weight transpose+cast: all 6 weights, 1 launch --------
__global__ __launch_bounds__(256) void wtrans_all_kernel(
    const float* __restrict__ Wq, const float* __restrict__ Wk,
    const float* __restrict__ Wv, const float* __restrict__ Wo,
    const float* __restrict__ W1, const float* __restrict__ W2,
    u16* __restrict__ Wqkvt, u16* __restrict__ Wot,
    u16* __restrict__ W1t, u16* __restrict__ W2t)
{
    const int bid = blockIdx.x;
    const float* W;
    u16* Wt;
    int K, N, nx, loc;
    if (bid < 4096) {
        loc = bid & 1023;
        const int wsel = bid >> 10;
        W = (wsel == 0) ? Wq : (wsel == 1) ? Wk : (wsel == 2) ? Wv : Wo;
        Wt = (wsel == 3) ? Wot : (Wqkvt + (size_t)wsel * 1024 * 1024);
        K = 1024; N = 1024; nx = 32;
    } else if (bid < 8192) {
        loc = bid - 4096; W = W1; Wt = W1t; K = 1024; N = 4096; nx = 128;
    } else {
        loc = bid - 8192; W = W2; Wt = W2t; K = 4096; N = 1024; nx = 32;
    }
    const int n0 = (loc % nx) * 32, k0 = (loc / nx) * 32;

    __shared__ float t[32][33];
    const int tx = threadIdx.x & 31, ty = threadIdx.x >> 5; // 32 x 8
#pragma unroll
    for (int i = 0; i < 4; ++i)
        t[ty + i * 8][tx] = W[(size_t)(k0 + ty + i * 8) * N + n0 + tx];
    __syncthreads();
#pragma unroll
    for (int i = 0; i < 4; ++i)
        Wt[(size_t)(n0 + ty + i * 8) * K + k0 + tx] = f2bf(t[tx][ty + i * 8]);
}

// ---------------- LayerNorm: f32 [rows][1024] -> bf16 ----------------------
__global__ __launch_bounds__(256) void ln_kernel(
    const float* __restrict__ X, const float* __restrict__ g,
    const float* __restrict__ sh, u16* __restrict__ Y)
{
    int row = blockIdx.x;
    const float4* xr = (const float4*)(X + (size_t)row * 1024);
    float4 x = xr[threadIdx.x];
    float s = x.x + x.y + x.z + x.w;
    float ss = x.x * x.x + x.y * x.y + x.z * x.z + x.w * x.w;
#pragma unroll
    for (int off = 32; off >= 1; off >>= 1) {
        s += __shfl_xor(s, off);
        ss += __shfl_xor(ss, off);
    }
    __shared__ float ps[4], pss[4];
    int wave = threadIdx.x >> 6, lane = threadIdx.x & 63;
    if (lane == 0) { ps[wave] = s; pss[wave] = ss; }
    __syncthreads();
    s = ps[0] + ps[1] + ps[2] + ps[3];
    ss = pss[0] + pss[1] + pss[2] + pss[3];
    float mean = s * (1.f / 1024.f);
    float var = ss * (1.f / 1024.f) - mean * mean;
    float rstd = rsqrtf(var + 1e-5f);
    int c = threadIdx.x * 4;
    ushort4 o;
    o.x = f2bf((x.x - mean) * rstd * g[c + 0] + sh[c + 0]);
    o.y = f2bf((x.y - mean) * rstd * g[c + 1] + sh[c + 1]);
    o.z = f2bf((x.z - mean) * rstd * g[c + 2] + sh[c + 2]);
    o.w = f2bf((x.w - mean) * rstd * g[c + 3] + sh[c + 3]);
    ((ushort4*)(Y + (size_t)row * 1024))[threadIdx.x] = o;
}

// ---------------- GEMM 128x128 (proven): C = A @ Bt^T ----------------------
// BK=32, 4 waves, 3-deep staging + counted vmcnt(4), single raw barrier per
// K-step. NEW (R13): XCD-chunked block order, col-panel-contiguous per XCD —
// each XCD's L2 keeps its B col-panel slice hot while A streams via L3.
// Requires nwg % 8 == 0 (all callers: 1536/512/512).
template <int OUT_BF16, int HAS_BIAS, int HAS_RES, int ACT_GELU>
__global__ __launch_bounds__(256) void gemm_kernel(
    const u16* __restrict__ A, const u16* __restrict__ Bt,
    const float* __restrict__ bias, const float* __restrict__ res,
    void* __restrict__ Cout, int M, int N, int K)
{
    __shared__ u16 As[3][128 * 32];
    __shared__ u16 Bs[3][128 * 32];
    const int tid = threadIdx.x;
    const int lane = tid & 63, wave = tid >> 6;
    const int wm = wave >> 1, wn = wave & 1;
    const int l16 = lane & 15, lg = lane >> 4;

    // XCD-chunked, col-major work order: same-XCD blocks share a B col-panel
    const int gx = gridDim.x, gy = gridDim.y;
    const int nwg = gx * gy;
    const int orig = (int)blockIdx.y * gx + (int)blockIdx.x;
    const int work = (orig & 7) * (nwg >> 3) + (orig >> 3);
    const int rowBase = (work % gy) * 128;
    const int colBase = (work / gy) * 128;

    f32x4 acc[4][4];
#pragma unroll
    for (int m = 0; m < 4; ++m)
#pragma unroll
        for (int n = 0; n < 4; ++n) acc[m][n] = (f32x4){0.f, 0.f, 0.f, 0.f};

#define GSTAGE(SB, KT)                                                        \
    {                                                                         \
        _Pragma("unroll")                                                     \
        for (int i_ = 0; i_ < 2; ++i_) {                                      \
            int eo = tid * 8 + i_ * 2048;                                     \
            int r_ = eo >> 5, c_ = eo & 31;                                   \
            async_cp16(A + (size_t)(rowBase + r_) * K + (KT) + c_, As[SB] + eo); \
            async_cp16(Bt + (size_t)(colBase + r_) * K + (KT) + c_, Bs[SB] + eo); \
        }                                                                     \
    }

    const int nt = K >> 5;
    GSTAGE(0, 0);
    GSTAGE(1, 32);
    wait_vm4();
    __builtin_amdgcn_s_barrier();
    __builtin_amdgcn_sched_barrier(0);

    int cur = 0, stg = 2;
    for (int t = 0; t < nt; ++t) {
        const bool more = (t + 2 < nt);
        if (more) GSTAGE(stg, (t + 2) * 32);

        bf16x8 af[4], bfr[4];
#pragma unroll
        for (int m = 0; m < 4; ++m)
            af[m] = *(const bf16x8*)(As[cur] + (wm * 64 + m * 16 + l16) * 32 + lg * 8);
#pragma unroll
        for (int n = 0; n < 4; ++n)
            bfr[n] = *(const bf16x8*)(Bs[cur] + (wn * 64 + n * 16 + l16) * 32 + lg * 8);
#pragma unroll
        for (int m = 0; m < 4; ++m)
#pragma unroll
            for (int n = 0; n < 4; ++n)
                acc[m][n] = __builtin_amdgcn_mfma_f32_16x16x32_bf16(
                    af[m], bfr[n], acc[m][n], 0, 0, 0);

        if (more) wait_vm4(); else wait_vm0();
        __builtin_amdgcn_s_barrier();
        __builtin_amdgcn_sched_barrier(0);
        cur = (cur == 2) ? 0 : cur + 1;
        stg = (stg == 2) ? 0 : stg + 1;
    }
#undef GSTAGE

#pragma unroll
    for (int m = 0; m < 4; ++m) {
#pragma unroll
        for (int n = 0; n < 4; ++n) {
            int gr0 = rowBase + wm * 64 + m * 16 + lg * 4;
            int gc = colBase + wn * 64 + n * 16 + l16;
            float bv = HAS_BIAS ? bias[gc] : 0.f;
#pragma unroll
            for (int r = 0; r < 4; ++r) {
                float v = acc[m][n][r] + bv;
                if (ACT_GELU) v = gelu_fn(v);
                if (HAS_RES) v += res[(size_t)(gr0 + r) * N + gc];
                if (OUT_BF16)
                    ((u16*)Cout)[(size_t)(gr0 + r) * N + gc] = f2bf(v);
                else
                    ((float*)Cout)[(size_t)(gr0 + r) * N + gc] = v;
            }
        }
    }
}

// ---------------- GEMM 256x256, BK=64, 8 waves, 8-phase (R8-proven) --------
template <int OUT_BF16, int HAS_BIAS, int ACT_GELU>
__global__ __launch_bounds__(512, 2) void gemm8p_kernel(
    const u16* __restrict__ A, const u16* __restrict__ Bt,
    const float* __restrict__ bias, void* __restrict__ Cout,
    int M, int N, int K)
{
    __shared__ u16 As[2][256 * 64];
    __shared__ u16 Bs[2][256 * 64];
    const int tid = threadIdx.x;
    const int lane = tid & 63, wave = tid >> 6;
    const int wm = wave >> 2, wn = wave & 3;     // 2 x 4 wave grid
    const int l16 = lane & 15, lg = lane >> 4;

    const int gx = gridDim.x, gy = gridDim.y;
    const int nwg = gx * gy;
    const int orig = (int)blockIdx.y * gx + (int)blockIdx.x;
    const int work = (orig & 7) * (nwg >> 3) + (orig >> 3);
    const int colBase = (work / gy) * 256;
    const int rowBase = (work % gy) * 256;

    f32x4 acc[8][4];
#pragma unroll
    for (int m = 0; m < 8; ++m)
#pragma unroll
        for (int n = 0; n < 4; ++n) acc[m][n] = (f32x4){0.f, 0.f, 0.f, 0.f};

#define STRIP(SB, KT, S)                                                      \
    {                                                                         \
        int tl_ = tid & 255, hf_ = tid >> 8;                                  \
        int r_ = hf_ * 128 + (S) * 32 + (tl_ >> 3);                           \
        int gl_ = (tl_ & 7) ^ (r_ & 7);                                       \
        int dst_ = r_ * 64 + (tl_ & 7) * 8;                                   \
        async_cp16(A + (size_t)(rowBase + r_) * K + (KT) + gl_ * 8, As[SB] + dst_); \
        async_cp16(Bt + (size_t)(colBase + r_) * K + (KT) + gl_ * 8, Bs[SB] + dst_); \
    }
#define FRAG_OFF(row, G) ((row) * 64 + (((G) ^ ((row) & 7)) * 8))

#define PHASE(BUF, QUAD, LOADB, STAGE, WAITN)                                 \
    {                                                                         \
        __builtin_amdgcn_sched_barrier(0);                                    \
        if (LOADB) {                                                          \
            _Pragma("unroll")                                                 \
            for (int nf = 0; nf < 4; ++nf) {                                  \
                int row = wn * 64 + nf * 16 + l16;                            \
                _Pragma("unroll")                                             \
                for (int ks = 0; ks < 2; ++ks)                                \
                    bfr[nf][ks] = *(const bf16x8*)(Bs[BUF] + FRAG_OFF(row, lg + ks * 4)); \
            }                                                                 \
        }                                                                     \
        bf16x8 af[2][2];                                                      \
        _Pragma("unroll")                                                     \
        for (int mi = 0; mi < 2; ++mi) {                                      \
            int row = wm * 128 + (QUAD) * 32 + mi * 16 + l16;                 \
            _Pragma("unroll")                                                 \
            for (int ks = 0; ks < 2; ++ks)                                    \
                af[mi][ks] = *(const bf16x8*)(As[BUF] + FRAG_OFF(row, lg + ks * 4)); \
        }                                                                     \
        STAGE;                                                                \
        __builtin_amdgcn_sched_barrier(0);                                    \
        __builtin_amdgcn_s_barrier();                                         \
        __builtin_amdgcn_s_setprio(1);                                        \
        _Pragma("unroll")                                                     \
        for (int mi = 0; mi < 2; ++mi)                                        \
            _Pragma("unroll")                                                 \
            for (int nf = 0; nf < 4; ++nf)                                    \
                _Pragma("unroll")                                             \
                for (int ks = 0; ks < 2; ++ks)                                \
                    acc[(QUAD) * 2 + mi][nf] =                                \
                        __builtin_amdgcn_mfma_f32_16x16x32_bf16(              \
                            af[mi][ks], bfr[nf][ks], acc[(QUAD) * 2 + mi][nf], 0, 0, 0); \
        __builtin_amdgcn_s_setprio(0);                                        \
        __builtin_amdgcn_sched_barrier(0);                                    \
        WAITN;                                                                \
        __builtin_amdgcn_s_barrier();                                         \
    }

    const int nt = K >> 6;
    const int half = nt >> 1;

    STRIP(0, 0, 0); STRIP(0, 0, 1); STRIP(0, 0, 2); STRIP(0, 0, 3);
    STRIP(1, 64, 0); STRIP(1, 64, 1); STRIP(1, 64, 2);
    wait_vm6();
    __builtin_amdgcn_s_barrier();
    __builtin_amdgcn_sched_barrier(0);

    for (int it = 0; it < half; ++it) {
        const int kt1 = (it * 2 + 1) << 6;
        const int kt2 = (it * 2 + 2) << 6;
        const int kt3 = (it * 2 + 3) << 6;
        const bool more = (it + 1 < half);
        bf16x8 bfr[4][2];
        PHASE(0, 0, 1, STRIP(1, kt1, 3), ((void)0));
        PHASE(0, 1, 0, if (more) STRIP(0, kt2, 0), ((void)0));
        PHASE(0, 2, 0, if (more) STRIP(0, kt2, 1), ((void)0));
        PHASE(0, 3, 0, if (more) STRIP(0, kt2, 2),
              if (more) wait_vm6(); else wait_vm0());
        PHASE(1, 0, 1, if (more) STRIP(0, kt2, 3), ((void)0));
        PHASE(1, 1, 0, if (more) STRIP(1, kt3, 0), ((void)0));
        PHASE(1, 2, 0, if (more) STRIP(1, kt3, 1), ((void)0));
        PHASE(1, 3, 0, if (more) STRIP(1, kt3, 2),
              if (more) wait_vm6(); else wait_vm0());
    }
#undef STRIP
#undef FRAG_OFF
#undef PHASE

#pragma unroll
    for (int mf = 0; mf < 8; ++mf) {
#pragma unroll
        for (int nf = 0; nf < 4; ++nf) {
            int gr0 = rowBase + wm * 128 + mf * 16 + lg * 4;
            int gc = colBase + wn * 64 + nf * 16 + l16;
            float bv = HAS_BIAS ? bias[gc] : 0.f;
#pragma unroll
            for (int r = 0; r < 4; ++r) {
                float v = acc[mf][nf][r] + bv;
                if (ACT_GELU) v = gelu_fn(v);
                if (OUT_BF16)
                    ((u16*)Cout)[(size_t)(gr0 + r) * N + gc] = f2bf(v);
                else
                    ((float*)Cout)[(size_t)(gr0 + r) * N + gc] = v;
            }
        }
    }
}

// ---------------- causal flash attention (R12-proven: balanced grid) -------
__global__ __launch_bounds__(512) void attn_kernel(
    const u16* __restrict__ QKV, u16* __restrict__ Z)
{
    __shared__ u16 Ks[2][64 * 64];
    __shared__ u16 Vt[2][64 * 64];
    __shared__ u16 Pl[8][32 * 64];

    const int bh = blockIdx.x;               // 0..63
    const int b = bh >> 4, h = bh & 15;
    const int g = blockIdx.y;                // 0..7
    const int qt = (g < 4) ? (7 - g) : (g - 4);  // complementary at stride 256
    const int tid = threadIdx.x;
    const int wave = tid >> 6, lane = tid & 63;
    const int l16 = lane & 15, lg = lane >> 4;

    const size_t baseQ = (size_t)b * 2048 * 3072 + (size_t)h * 64;
    const size_t baseK = baseQ + 1024;
    const size_t baseV = baseQ + 2048;

    const int q0w = qt * 256 + wave * 32;

    // Q fragments, pre-scaled by 1/sqrt(64)=0.125 (exact pow2)
    bf16x8 aq[2][2];
#pragma unroll
    for (int mq = 0; mq < 2; ++mq) {
        const u16* qp = QKV + baseQ + (size_t)(q0w + mq * 16 + l16) * 3072;
#pragma unroll
        for (int hf = 0; hf < 2; ++hf) {
            bf16x8 v = *(const bf16x8*)(qp + hf * 32 + lg * 8);
#pragma unroll
            for (int j = 0; j < 8; ++j) v[j] = (__bf16)((float)v[j] * 0.125f);
            aq[mq][hf] = v;
        }
    }

    f32x4 o[2][4];
    float lrow[2][4];
#pragma unroll
    for (int mq = 0; mq < 2; ++mq)
#pragma unroll
        for (int i = 0; i < 4; ++i) {
            o[mq][i] = (f32x4){0.f, 0.f, 0.f, 0.f};
            lrow[mq][i] = 0.f;
        }

    const int nch = 4 * qt + 4;

    // 512 threads: one cp16 each covers the 64x64 K tile (xor-swizzled rows)
#define STAGE_K(BUF, KB)                                                      \
    {                                                                         \
        int n = tid;                                                          \
        int r = n >> 3;                                                       \
        int lb = ((n & 7) * 16) ^ ((r & 7) << 4);                             \
        async_cp16(QKV + baseK + (size_t)((KB) + r) * 3072 + (lb >> 1),       \
                   Ks[BUF] + n * 8);                                          \
    }
    // wave w owns d rows w*8..w*8+7; lane = k (64 lanes)
#define LOAD_V(KB, V0)                                                        \
    {                                                                         \
        const u16* vp = QKV + baseV + (size_t)((KB) + lane) * 3072;           \
        V0 = *(const u16x8*)(vp + wave * 8);                                  \
    }
#define WRITE_V(BUF, V0)                                                      \
    {                                                                         \
        _Pragma("unroll")                                                     \
        for (int j = 0; j < 8; ++j) {                                         \
            int d = wave * 8 + j;                                             \
            int byt = (d * 128 + lane * 2) ^ ((d & 7) << 4);                  \
            Vt[BUF][byt >> 1] = V0[j];                                        \
        }                                                                     \
    }
#define SOFTMAX_BODY(DIAG)                                                    \
    _Pragma("unroll")                                                         \
    for (int mq = 0; mq < 2; ++mq) {                                          \
        _Pragma("unroll")                                                     \
        for (int r = 0; r < 4; ++r) {                                         \
            float sv0 = s[mq][0][r];                                          \
            float sv1 = s[mq][1][r];                                          \
            float sv2 = s[mq][2][r];                                          \
            float sv3 = s[mq][3][r];                                          \
            if (DIAG) {                                                       \
                const int q = q0w + mq * 16 + lg * 4 + r;                     \
                if (kbase + 0 + l16 > q)  sv0 = -1e30f;                       \
                if (kbase + 16 + l16 > q) sv1 = -1e30f;                       \
                if (kbase + 32 + l16 > q) sv2 = -1e30f;                       \
                if (kbase + 48 + l16 > q) sv3 = -1e30f;                       \
            }                                                                 \
            float p0 = __expf(sv0), p1 = __expf(sv1);                         \
            float p2 = __expf(sv2), p3 = __expf(sv3);                         \
            lrow[mq][r] += (p0 + p1) + (p2 + p3);                             \
            int rowm = mq * 16 + lg * 4 + r;                                  \
            int rb = rowm * 128, swz = (rowm & 7) << 4;                       \
            Pl[wave][(rb + ((0  + 2 * l16) ^ swz)) >> 1] = f2bf(p0);          \
            Pl[wave][(rb + ((32 + 2 * l16) ^ swz)) >> 1] = f2bf(p1);          \
            Pl[wave][(rb + ((64 + 2 * l16) ^ swz)) >> 1] = f2bf(p2);          \
            Pl[wave][(rb + ((96 + 2 * l16) ^ swz)) >> 1] = f2bf(p3);          \
        }                                                                     \
    }

    // ---- prologue: stage chunk 0 into buffer 0 ----
    {
        STAGE_K(0, 0);
        u16x8 v0;
        LOAD_V(0, v0);
        WRITE_V(0, v0);
    }
    __syncthreads();

    int cur = 0;
    for (int kc = 0; kc < nch; ++kc) {
        const int kbase = kc * 64;
        const int nxt = cur ^ 1;
        const bool more = (kc + 1 < nch);
        u16x8 nv0;
        if (more) {
            STAGE_K(nxt, kbase + 64);      // async global->LDS, drains at barrier
            LOAD_V(kbase + 64, nv0);       // global->reg, written post-compute
        }

        if (q0w + 31 >= kbase) {
            // ---- QK^T: S[32 q][64 k] ----
            f32x4 s[2][4];
#pragma unroll
            for (int mq = 0; mq < 2; ++mq)
#pragma unroll
                for (int t = 0; t < 4; ++t) s[mq][t] = (f32x4){0.f, 0.f, 0.f, 0.f};
            __builtin_amdgcn_s_setprio(1);
#pragma unroll
            for (int t = 0; t < 4; ++t) {
                int row = t * 16 + l16;
                int swz = (row & 7) << 4;
                bf16x8 bk0 = *(const bf16x8*)(Ks[cur] + ((row * 128 + ((16 * lg) ^ swz)) >> 1));
                bf16x8 bk1 = *(const bf16x8*)(Ks[cur] + ((row * 128 + ((64 + 16 * lg) ^ swz)) >> 1));
#pragma unroll
                for (int mq = 0; mq < 2; ++mq) {
                    s[mq][t] = __builtin_amdgcn_mfma_f32_16x16x32_bf16(aq[mq][0], bk0, s[mq][t], 0, 0, 0);
                    s[mq][t] = __builtin_amdgcn_mfma_f32_16x16x32_bf16(aq[mq][1], bk1, s[mq][t], 0, 0, 0);
                }
            }
            __builtin_amdgcn_s_setprio(0);

            // ---- max-free softmax + P -> LDS ----
            const bool diag = (kbase + 63 > q0w);
            if (diag) { SOFTMAX_BODY(1) } else { SOFTMAX_BODY(0) }

            // ---- PV: O[32 q][64 d] += P @ V ----
            bf16x8 bv[2][4];
#pragma unroll
            for (int kst = 0; kst < 2; ++kst)
#pragma unroll
                for (int ct = 0; ct < 4; ++ct) {
                    int d = ct * 16 + l16;
                    bv[kst][ct] = *(const bf16x8*)(Vt[cur] + ((d * 128 + ((64 * kst + 16 * lg) ^ ((d & 7) << 4))) >> 1));
                }
            __builtin_amdgcn_s_setprio(1);
#pragma unroll
            for (int mq = 0; mq < 2; ++mq) {
                int rowm = mq * 16 + l16;
                int swz = (rowm & 7) << 4;
                bf16x8 ap0 = *(const bf16x8*)(&Pl[wave][(rowm * 128 + ((16 * lg) ^ swz)) >> 1]);
                bf16x8 ap1 = *(const bf16x8*)(&Pl[wave][(rowm * 128 + ((64 + 16 * lg) ^ swz)) >> 1]);
#pragma unroll
                for (int ct = 0; ct < 4; ++ct) {
                    o[mq][ct] = __builtin_amdgcn_mfma_f32_16x16x32_bf16(ap0, bv[0][ct], o[mq][ct], 0, 0, 0);
                    o[mq][ct] = __builtin_amdgcn_mfma_f32_16x16x32_bf16(ap1, bv[1][ct], o[mq][ct], 0, 0, 0);
                }
            }
            __builtin_amdgcn_s_setprio(0);
        }

        if (more) { WRITE_V(nxt, nv0); }   // vmcnt wait lands here (late)
        __syncthreads();                    // drains own async K + V writes
        cur = nxt;
    }

    // ---- epilogue: reduce l across the 16 k-lanes, normalize, store ----
#pragma unroll
    for (int mq = 0; mq < 2; ++mq)
#pragma unroll
        for (int r = 0; r < 4; ++r) {
            float l = lrow[mq][r];
            l += __shfl_xor(l, 1);
            l += __shfl_xor(l, 2);
            l += __shfl_xor(l, 4);
            l += __shfl_xor(l, 8);
            float inv = 1.f / l;
            size_t zr = ((size_t)b * 2048 + q0w + mq * 16 + lg * 4 + r) * 1024 + h * 64;
#pragma unroll
            for (int ct = 0; ct < 4; ++ct)
                Z[zr + ct * 16 + l16] = f2bf(o[mq][ct][r] * inv);
        }
#undef STAGE_K
#undef LOAD_V
#undef WRITE_V
#undef SOFTMAX_BODY
}

// ---------------------------------------------------------------------------
extern "C" void kernel_launch(void* const* d_in, const int* in_sizes, int n_in,
                              void* d_out, int out_size, void* d_ws, size_t ws_size,
                              hipStream_t stream)
{
    const float* X  = (const float*)d_in[0];
    const float* Wq = (const float*)d_in[1];
    const float* Wk = (const float*)d_in[2];
    const float* Wv = (const float*)d_in[3];
    const float* Wo = (const float*)d_in[4];
    const float* bo = (const float*)d_in[5];
    const float* W1 = (const float*)d_in[6];
    const float* b1 = (const float*)d_in[7];
    const float* W2 = (const float*)d_in[8];
    const float* b2 = (const float*)d_in[9];
    const float* g1 = (const float*)d_in[10];
    const float* s1 = (const float*)d_in[11];
    const float* g2 = (const float*)d_in[12];
    const float* s2 = (const float*)d_in[13];
    float* out = (float*)d_out;

    uint8_t* ws = (uint8_t*)d_ws;
    const size_t MB = 1024 * 1024;
    u16* Wqkvt = (u16*)(ws + 0 * MB);   // [3072][1024] bf16 (Q,K,V stacked)
    u16* Wot   = (u16*)(ws + 6 * MB);   // [1024][1024]
    u16* W1t   = (u16*)(ws + 8 * MB);   // [4096][1024]
    u16* W2t   = (u16*)(ws + 16 * MB);  // [1024][4096]
    u16* Yb    = (u16*)(ws + 24 * MB);  // [8192][1024] LN1 out
    u16* QKVb  = (u16*)(ws + 40 * MB);  // [8192][3072]
    u16* Zb    = (u16*)(ws + 24 * MB);  // reuse Yb (dead after QKV gemm)
    u16* Y2b   = (u16*)(ws + 40 * MB);  // reuse QKVb (dead after attention)
    u16* Hb    = (u16*)(ws + 56 * MB);  // [8192][4096]

    // 1) weight prep (single fused launch, 12288 tiles)
    wtrans_all_kernel<<<12288, 256, 0, stream>>>(Wq, Wk, Wv, Wo, W1, W2,
                                                 Wqkvt, Wot, W1t, W2t);

    // 2) LN1
    ln_kernel<<<8192, 256, 0, stream>>>(X, g1, s1, Yb);

    // 3) fused QKV projection (128^2 kernel; 1536 blocks, XCD-chunked)
    gemm_kernel<1, 0, 0, 0><<<dim3(24, 64), 256, 0, stream>>>(Yb, Wqkvt, nullptr, nullptr, QKVb, 8192, 3072, 1024);

    // 4) attention (QBLK=256, 8 waves, CU-balanced grid 64x8)
    attn_kernel<<<dim3(64, 8), 512, 0, stream>>>(QKVb, Zb);

    // 5) Wo projection + bo + shortcut X -> X1 (fp32 in d_out)
    gemm_kernel<0, 1, 1, 0><<<dim3(8, 64), 256, 0, stream>>>(Zb, Wot, bo, X, out, 8192, 1024, 1024);

    // 6) LN2
    ln_kernel<<<8192, 256, 0, stream>>>(out, g2, s2, Y2b);

    // 7) FFN up + gelu (8-phase 256^2; grid 16x32 = 512 % 8 == 0, balanced)
    gemm8p_kernel<1, 1, 1><<<dim3(16, 32), 512, 0, stream>>>(Y2b, W1t, b1, Hb, 8192, 4096, 1024);

    // 8) FFN down + b2 + residual (in-place on d_out; XCD-chunked: each XCD
    //    owns one 1MB B col-panel, L2-resident; A streams via L3)
    gemm_kernel<0, 1, 1, 0><<<dim3(8, 64), 256, 0, stream>>>(Hb, W2t, b2, out, out, 8192, 1024, 4096);
}

// Round 14
// 381.139 us; speedup vs baseline: 1.0828x; 1.0828x over previous
//
#include <hip/hip_runtime.h>
#include <cstdint>
#include <cstddef>

#define DEV static __device__ __forceinline__

typedef __bf16 bf16x8 __attribute__((ext_vector_type(8)));
typedef float f32x4 __attribute__((ext_vector_type(4)));
typedef unsigned short u16x8 __attribute__((ext_vector_type(8)));
typedef unsigned short u16;

DEV u16 f2bf(float f) { __bf16 b = (__bf16)f; return __builtin_bit_cast(u16, b); }
DEV float bf2f(u16 u) { unsigned v = (unsigned)u << 16; return __builtin_bit_cast(float, v); }

DEV void async_cp16(const void* g, void* l) {
    __builtin_amdgcn_global_load_lds(
        (const __attribute__((address_space(1))) void*)g,
        (__attribute__((address_space(3))) void*)l, 16, 0, 0);
}

DEV void wait_vm6() { asm volatile("s_waitcnt vmcnt(6)" ::: "memory"); }
DEV void wait_vm4() { asm volatile("s_waitcnt vmcnt(4)" ::: "memory"); }
DEV void wait_vm0() { asm volatile("s_waitcnt vmcnt(0)" ::: "memory"); }

// gelu with module's custom 0.04715 constant; overflow-safe tanh
DEV float gelu_fn(float x) {
    const float c = 0.7978845608028654f; // sqrt(2/pi)
    float t = c * (x + 0.04715f * x * x * x);
    float e = __expf(2.f * t);
    float th = 1.f - 2.f / (e + 1.f); // tanh(t), safe at +-inf
    return 0.5f * x * (1.f + th);
}

// ------------- fused weight transpose+cast: all 6 weights, 1 launch --------
__global__ __launch_bounds__(256) void wtrans_all_kernel(
    const float* __restrict__ Wq, const float* __restrict__ Wk,
    const float* __restrict__ Wv, const float* __restrict__ Wo,
    const float* __restrict__ W1, const float* __restrict__ W2,
    u16* __restrict__ Wqkvt, u16* __restrict__ Wot,
    u16* __restrict__ W1t, u16* __restrict__ W2t)
{
    const int bid = blockIdx.x;
    const float* W;
    u16* Wt;
    int K, N, nx, loc;
    if (bid < 4096) {
        loc = bid & 1023;
        const int wsel = bid >> 10;
        W = (wsel == 0) ? Wq : (wsel == 1) ? Wk : (wsel == 2) ? Wv : Wo;
        Wt = (wsel == 3) ? Wot : (Wqkvt + (size_t)wsel * 1024 * 1024);
        K = 1024; N = 1024; nx = 32;
    } else if (bid < 8192) {
        loc = bid - 4096; W = W1; Wt = W1t; K = 1024; N = 4096; nx = 128;
    } else {
        loc = bid - 8192; W = W2; Wt = W2t; K = 4096; N = 1024; nx = 32;
    }
    const int n0 = (loc % nx) * 32, k0 = (loc / nx) * 32;

    __shared__ float t[32][33];
    const int tx = threadIdx.x & 31, ty = threadIdx.x >> 5; // 32 x 8
#pragma unroll
    for (int i = 0; i < 4; ++i)
        t[ty + i * 8][tx] = W[(size_t)(k0 + ty + i * 8) * N + n0 + tx];
    __syncthreads();
#pragma unroll
    for (int i = 0; i < 4; ++i)
        Wt[(size_t)(n0 + ty + i * 8) * K + k0 + tx] = f2bf(t[tx][ty + i * 8]);
}

// ---------------- LayerNorm: f32 [rows][1024] -> bf16 ----------------------
__global__ __launch_bounds__(256) void ln_kernel(
    const float* __restrict__ X, const float* __restrict__ g,
    const float* __restrict__ sh, u16* __restrict__ Y)
{
    int row = blockIdx.x;
    const float4* xr = (const float4*)(X + (size_t)row * 1024);
    float4 x = xr[threadIdx.x];
    float s = x.x + x.y + x.z + x.w;
    float ss = x.x * x.x + x.y * x.y + x.z * x.z + x.w * x.w;
#pragma unroll
    for (int off = 32; off >= 1; off >>= 1) {
        s += __shfl_xor(s, off);
        ss += __shfl_xor(ss, off);
    }
    __shared__ float ps[4], pss[4];
    int wave = threadIdx.x >> 6, lane = threadIdx.x & 63;
    if (lane == 0) { ps[wave] = s; pss[wave] = ss; }
    __syncthreads();
    s = ps[0] + ps[1] + ps[2] + ps[3];
    ss = pss[0] + pss[1] + pss[2] + pss[3];
    float mean = s * (1.f / 1024.f);
    float var = ss * (1.f / 1024.f) - mean * mean;
    float rstd = rsqrtf(var + 1e-5f);
    int c = threadIdx.x * 4;
    ushort4 o;
    o.x = f2bf((x.x - mean) * rstd * g[c + 0] + sh[c + 0]);
    o.y = f2bf((x.y - mean) * rstd * g[c + 1] + sh[c + 1]);
    o.z = f2bf((x.z - mean) * rstd * g[c + 2] + sh[c + 2]);
    o.w = f2bf((x.w - mean) * rstd * g[c + 3] + sh[c + 3]);
    ((ushort4*)(Y + (size_t)row * 1024))[threadIdx.x] = o;
}

// ---------------- FFN-down split-K combine: out += P0 + P1 + b2 ------------
__global__ __launch_bounds__(256) void combine_kernel(
    const u16* __restrict__ P0, const u16* __restrict__ P1,
    const float* __restrict__ b2, float* __restrict__ out)
{
    const size_t row = blockIdx.x;
    const int c = threadIdx.x * 4;
    const size_t off = row * 1024 + c;
    ushort4 a = *(const ushort4*)(P0 + off);
    ushort4 b = *(const ushort4*)(P1 + off);
    float4 o = *(float4*)(out + off);
    o.x += bf2f(a.x) + bf2f(b.x) + b2[c + 0];
    o.y += bf2f(a.y) + bf2f(b.y) + b2[c + 1];
    o.z += bf2f(a.z) + bf2f(b.z) + b2[c + 2];
    o.w += bf2f(a.w) + bf2f(b.w) + b2[c + 3];
    *(float4*)(out + off) = o;
}

// ---------------- GEMM 128x128 (R12-proven): C = A @ Bt^T ------------------
// BK=32, 4 waves, 3-deep staging + counted vmcnt(4), single raw barrier per
// K-step (never drains the prefetch pipeline to 0 mid-loop).
template <int OUT_BF16, int HAS_BIAS, int HAS_RES, int ACT_GELU>
__global__ __launch_bounds__(256) void gemm_kernel(
    const u16* __restrict__ A, const u16* __restrict__ Bt,
    const float* __restrict__ bias, const float* __restrict__ res,
    void* __restrict__ Cout, int M, int N, int K)
{
    __shared__ u16 As[3][128 * 32];
    __shared__ u16 Bs[3][128 * 32];
    const int tid = threadIdx.x;
    const int lane = tid & 63, wave = tid >> 6;
    const int wm = wave >> 1, wn = wave & 1;
    const int l16 = lane & 15, lg = lane >> 4;
    const int rowBase = blockIdx.y * 128;
    const int colBase = blockIdx.x * 128;

    f32x4 acc[4][4];
#pragma unroll
    for (int m = 0; m < 4; ++m)
#pragma unroll
        for (int n = 0; n < 4; ++n) acc[m][n] = (f32x4){0.f, 0.f, 0.f, 0.f};

#define GSTAGE(SB, KT)                                                        \
    {                                                                         \
        _Pragma("unroll")                                                     \
        for (int i_ = 0; i_ < 2; ++i_) {                                      \
            int eo = tid * 8 + i_ * 2048;                                     \
            int r_ = eo >> 5, c_ = eo & 31;                                   \
            async_cp16(A + (size_t)(rowBase + r_) * K + (KT) + c_, As[SB] + eo); \
            async_cp16(Bt + (size_t)(colBase + r_) * K + (KT) + c_, Bs[SB] + eo); \
        }                                                                     \
    }

    const int nt = K >> 5;
    GSTAGE(0, 0);
    GSTAGE(1, 32);
    wait_vm4();
    __builtin_amdgcn_s_barrier();
    __builtin_amdgcn_sched_barrier(0);

    int cur = 0, stg = 2;
    for (int t = 0; t < nt; ++t) {
        const bool more = (t + 2 < nt);
        if (more) GSTAGE(stg, (t + 2) * 32);

        bf16x8 af[4], bfr[4];
#pragma unroll
        for (int m = 0; m < 4; ++m)
            af[m] = *(const bf16x8*)(As[cur] + (wm * 64 + m * 16 + l16) * 32 + lg * 8);
#pragma unroll
        for (int n = 0; n < 4; ++n)
            bfr[n] = *(const bf16x8*)(Bs[cur] + (wn * 64 + n * 16 + l16) * 32 + lg * 8);
#pragma unroll
        for (int m = 0; m < 4; ++m)
#pragma unroll
            for (int n = 0; n < 4; ++n)
                acc[m][n] = __builtin_amdgcn_mfma_f32_16x16x32_bf16(
                    af[m], bfr[n], acc[m][n], 0, 0, 0);

        if (more) wait_vm4(); else wait_vm0();
        __builtin_amdgcn_s_barrier();
        __builtin_amdgcn_sched_barrier(0);
        cur = (cur == 2) ? 0 : cur + 1;
        stg = (stg == 2) ? 0 : stg + 1;
    }
#undef GSTAGE

#pragma unroll
    for (int m = 0; m < 4; ++m) {
#pragma unroll
        for (int n = 0; n < 4; ++n) {
            int gr0 = rowBase + wm * 64 + m * 16 + lg * 4;
            int gc = colBase + wn * 64 + n * 16 + l16;
            float bv = HAS_BIAS ? bias[gc] : 0.f;
#pragma unroll
            for (int r = 0; r < 4; ++r) {
                float v = acc[m][n][r] + bv;
                if (ACT_GELU) v = gelu_fn(v);
                if (HAS_RES) v += res[(size_t)(gr0 + r) * N + gc];
                if (OUT_BF16)
                    ((u16*)Cout)[(size_t)(gr0 + r) * N + gc] = f2bf(v);
                else
                    ((float*)Cout)[(size_t)(gr0 + r) * N + gc] = v;
            }
        }
    }
}

// ---------------- GEMM 256x256, BK=64, 8 waves, 8-phase (R8-proven) --------
// R14: generalized with ldk (row stride != K-loop) + split-K decode:
// grid y = rowTiles * nsplit; ks = (work%gy)/rowTiles selects K-slice
// (A,Bt += ks*koff) and output buffer ((u16*)Cout + ks*coff, bf16 partials).
template <int OUT_BF16, int HAS_BIAS, int ACT_GELU>
__global__ __launch_bounds__(512, 2) void gemm8p_kernel(
    const u16* __restrict__ A, const u16* __restrict__ Bt,
    const float* __restrict__ bias, void* __restrict__ Cout,
    int M, int N, int K, int ldk, int rowTiles, int koff, size_t coff)
{
    __shared__ u16 As[2][256 * 64];
    __shared__ u16 Bs[2][256 * 64];
    const int tid = threadIdx.x;
    const int lane = tid & 63, wave = tid >> 6;
    const int wm = wave >> 2, wn = wave & 3;     // 2 x 4 wave grid
    const int l16 = lane & 15, lg = lane >> 4;

    const int gx = gridDim.x, gy = gridDim.y;
    const int nwg = gx * gy;
    const int orig = (int)blockIdx.y * gx + (int)blockIdx.x;
    const int work = (orig & 7) * (nwg >> 3) + (orig >> 3);
    const int colBase = (work / gy) * 256;
    const int wy = work % gy;
    const int rowBase = (wy % rowTiles) * 256;
    const int ks = wy / rowTiles;
    A += (size_t)ks * koff;
    Bt += (size_t)ks * koff;

    f32x4 acc[8][4];
#pragma unroll
    for (int m = 0; m < 8; ++m)
#pragma unroll
        for (int n = 0; n < 4; ++n) acc[m][n] = (f32x4){0.f, 0.f, 0.f, 0.f};

#define STRIP(SB, KT, S)                                                      \
    {                                                                         \
        int tl_ = tid & 255, hf_ = tid >> 8;                                  \
        int r_ = hf_ * 128 + (S) * 32 + (tl_ >> 3);                           \
        int gl_ = (tl_ & 7) ^ (r_ & 7);                                       \
        int dst_ = r_ * 64 + (tl_ & 7) * 8;                                   \
        async_cp16(A + (size_t)(rowBase + r_) * ldk + (KT) + gl_ * 8, As[SB] + dst_); \
        async_cp16(Bt + (size_t)(colBase + r_) * ldk + (KT) + gl_ * 8, Bs[SB] + dst_); \
    }
#define FRAG_OFF(row, G) ((row) * 64 + (((G) ^ ((row) & 7)) * 8))

#define PHASE(BUF, QUAD, LOADB, STAGE, WAITN)                                 \
    {                                                                         \
        __builtin_amdgcn_sched_barrier(0);                                    \
        if (LOADB) {                                                          \
            _Pragma("unroll")                                                 \
            for (int nf = 0; nf < 4; ++nf) {                                  \
                int row = wn * 64 + nf * 16 + l16;                            \
                _Pragma("unroll")                                             \
                for (int ks_ = 0; ks_ < 2; ++ks_)                             \
                    bfr[nf][ks_] = *(const bf16x8*)(Bs[BUF] + FRAG_OFF(row, lg + ks_ * 4)); \
            }                                                                 \
        }                                                                     \
        bf16x8 af[2][2];                                                      \
        _Pragma("unroll")                                                     \
        for (int mi = 0; mi < 2; ++mi) {                                      \
            int row = wm * 128 + (QUAD) * 32 + mi * 16 + l16;                 \
            _Pragma("unroll")                                                 \
            for (int ks_ = 0; ks_ < 2; ++ks_)                                 \
                af[mi][ks_] = *(const bf16x8*)(As[BUF] + FRAG_OFF(row, lg + ks_ * 4)); \
        }                                                                     \
        STAGE;                                                                \
        __builtin_amdgcn_sched_barrier(0);                                    \
        __builtin_amdgcn_s_barrier();                                         \
        __builtin_amdgcn_s_setprio(1);                                        \
        _Pragma("unroll")                                                     \
        for (int mi = 0; mi < 2; ++mi)                                        \
            _Pragma("unroll")                                                 \
            for (int nf = 0; nf < 4; ++nf)                                    \
                _Pragma("unroll")                                             \
                for (int ks_ = 0; ks_ < 2; ++ks_)                             \
                    acc[(QUAD) * 2 + mi][nf] =                                \
                        __builtin_amdgcn_mfma_f32_16x16x32_bf16(              \
                            af[mi][ks_], bfr[nf][ks_], acc[(QUAD) * 2 + mi][nf], 0, 0, 0); \
        __builtin_amdgcn_s_setprio(0);                                        \
        __builtin_amdgcn_sched_barrier(0);                                    \
        WAITN;                                                                \
        __builtin_amdgcn_s_barrier();                                         \
    }

    const int nt = K >> 6;
    const int half = nt >> 1;

    STRIP(0, 0, 0); STRIP(0, 0, 1); STRIP(0, 0, 2); STRIP(0, 0, 3);
    STRIP(1, 64, 0); STRIP(1, 64, 1); STRIP(1, 64, 2);
    wait_vm6();
    __builtin_amdgcn_s_barrier();
    __builtin_amdgcn_sched_barrier(0);

    for (int it = 0; it < half; ++it) {
        const int kt1 = (it * 2 + 1) << 6;
        const int kt2 = (it * 2 + 2) << 6;
        const int kt3 = (it * 2 + 3) << 6;
        const bool more = (it + 1 < half);
        bf16x8 bfr[4][2];
        PHASE(0, 0, 1, STRIP(1, kt1, 3), ((void)0));
        PHASE(0, 1, 0, if (more) STRIP(0, kt2, 0), ((void)0));
        PHASE(0, 2, 0, if (more) STRIP(0, kt2, 1), ((void)0));
        PHASE(0, 3, 0, if (more) STRIP(0, kt2, 2),
              if (more) wait_vm6(); else wait_vm0());
        PHASE(1, 0, 1, if (more) STRIP(0, kt2, 3), ((void)0));
        PHASE(1, 1, 0, if (more) STRIP(1, kt3, 0), ((void)0));
        PHASE(1, 2, 0, if (more) STRIP(1, kt3, 1), ((void)0));
        PHASE(1, 3, 0, if (more) STRIP(1, kt3, 2),
              if (more) wait_vm6(); else wait_vm0());
    }
#undef STRIP
#undef FRAG_OFF
#undef PHASE

#pragma unroll
    for (int mf = 0; mf < 8; ++mf) {
#pragma unroll
        for (int nf = 0; nf < 4; ++nf) {
            int gr0 = rowBase + wm * 128 + mf * 16 + lg * 4;
            int gc = colBase + wn * 64 + nf * 16 + l16;
            float bv = HAS_BIAS ? bias[gc] : 0.f;
#pragma unroll
            for (int r = 0; r < 4; ++r) {
                float v = acc[mf][nf][r] + bv;
                if (ACT_GELU) v = gelu_fn(v);
                if (OUT_BF16)
                    ((u16*)Cout)[(size_t)ks * coff + (size_t)(gr0 + r) * N + gc] = f2bf(v);
                else
                    ((float*)Cout)[(size_t)ks * coff + (size_t)(gr0 + r) * N + gc] = v;
            }
        }
    }
}

// ---------------- causal flash attention (R12-proven: balanced grid) -------
__global__ __launch_bounds__(512) void attn_kernel(
    const u16* __restrict__ QKV, u16* __restrict__ Z)
{
    __shared__ u16 Ks[2][64 * 64];
    __shared__ u16 Vt[2][64 * 64];
    __shared__ u16 Pl[8][32 * 64];

    const int bh = blockIdx.x;               // 0..63
    const int b = bh >> 4, h = bh & 15;
    const int g = blockIdx.y;                // 0..7
    const int qt = (g < 4) ? (7 - g) : (g - 4);  // complementary at stride 256
    const int tid = threadIdx.x;
    const int wave = tid >> 6, lane = tid & 63;
    const int l16 = lane & 15, lg = lane >> 4;

    const size_t baseQ = (size_t)b * 2048 * 3072 + (size_t)h * 64;
    const size_t baseK = baseQ + 1024;
    const size_t baseV = baseQ + 2048;

    const int q0w = qt * 256 + wave * 32;

    // Q fragments, pre-scaled by 1/sqrt(64)=0.125 (exact pow2)
    bf16x8 aq[2][2];
#pragma unroll
    for (int mq = 0; mq < 2; ++mq) {
        const u16* qp = QKV + baseQ + (size_t)(q0w + mq * 16 + l16) * 3072;
#pragma unroll
        for (int hf = 0; hf < 2; ++hf) {
            bf16x8 v = *(const bf16x8*)(qp + hf * 32 + lg * 8);
#pragma unroll
            for (int j = 0; j < 8; ++j) v[j] = (__bf16)((float)v[j] * 0.125f);
            aq[mq][hf] = v;
        }
    }

    f32x4 o[2][4];
    float lrow[2][4];
#pragma unroll
    for (int mq = 0; mq < 2; ++mq)
#pragma unroll
        for (int i = 0; i < 4; ++i) {
            o[mq][i] = (f32x4){0.f, 0.f, 0.f, 0.f};
            lrow[mq][i] = 0.f;
        }

    const int nch = 4 * qt + 4;

    // 512 threads: one cp16 each covers the 64x64 K tile (xor-swizzled rows)
#define STAGE_K(BUF, KB)                                                      \
    {                                                                         \
        int n = tid;                                                          \
        int r = n >> 3;                                                       \
        int lb = ((n & 7) * 16) ^ ((r & 7) << 4);                             \
        async_cp16(QKV + baseK + (size_t)((KB) + r) * 3072 + (lb >> 1),       \
                   Ks[BUF] + n * 8);                                          \
    }
    // wave w owns d rows w*8..w*8+7; lane = k (64 lanes)
#define LOAD_V(KB, V0)                                                        \
    {                                                                         \
        const u16* vp = QKV + baseV + (size_t)((KB) + lane) * 3072;           \
        V0 = *(const u16x8*)(vp + wave * 8);                                  \
    }
#define WRITE_V(BUF, V0)                                                      \
    {                                                                         \
        _Pragma("unroll")                                                     \
        for (int j = 0; j < 8; ++j) {                                         \
            int d = wave * 8 + j;                                             \
            int byt = (d * 128 + lane * 2) ^ ((d & 7) << 4);                  \
            Vt[BUF][byt >> 1] = V0[j];                                        \
        }                                                                     \
    }
#define SOFTMAX_BODY(DIAG)                                                    \
    _Pragma("unroll")                                                         \
    for (int mq = 0; mq < 2; ++mq) {                                          \
        _Pragma("unroll")                                                     \
        for (int r = 0; r < 4; ++r) {                                         \
            float sv0 = s[mq][0][r];                                          \
            float sv1 = s[mq][1][r];                                          \
            float sv2 = s[mq][2][r];                                          \
            float sv3 = s[mq][3][r];                                          \
            if (DIAG) {                                                       \
                const int q = q0w + mq * 16 + lg * 4 + r;                     \
                if (kbase + 0 + l16 > q)  sv0 = -1e30f;                       \
                if (kbase + 16 + l16 > q) sv1 = -1e30f;                       \
                if (kbase + 32 + l16 > q) sv2 = -1e30f;                       \
                if (kbase + 48 + l16 > q) sv3 = -1e30f;                       \
            }                                                                 \
            float p0 = __expf(sv0), p1 = __expf(sv1);                         \
            float p2 = __expf(sv2), p3 = __expf(sv3);                         \
            lrow[mq][r] += (p0 + p1) + (p2 + p3);                             \
            int rowm = mq * 16 + lg * 4 + r;                                  \
            int rb = rowm * 128, swz = (rowm & 7) << 4;                       \
            Pl[wave][(rb + ((0  + 2 * l16) ^ swz)) >> 1] = f2bf(p0);          \
            Pl[wave][(rb + ((32 + 2 * l16) ^ swz)) >> 1] = f2bf(p1);          \
            Pl[wave][(rb + ((64 + 2 * l16) ^ swz)) >> 1] = f2bf(p2);          \
            Pl[wave][(rb + ((96 + 2 * l16) ^ swz)) >> 1] = f2bf(p3);          \
        }                                                                     \
    }

    // ---- prologue: stage chunk 0 into buffer 0 ----
    {
        STAGE_K(0, 0);
        u16x8 v0;
        LOAD_V(0, v0);
        WRITE_V(0, v0);
    }
    __syncthreads();

    int cur = 0;
    for (int kc = 0; kc < nch; ++kc) {
        const int kbase = kc * 64;
        const int nxt = cur ^ 1;
        const bool more = (kc + 1 < nch);
        u16x8 nv0;
        if (more) {
            STAGE_K(nxt, kbase + 64);      // async global->LDS, drains at barrier
            LOAD_V(kbase + 64, nv0);       // global->reg, written post-compute
        }

        if (q0w + 31 >= kbase) {
            // ---- QK^T: S[32 q][64 k] ----
            f32x4 s[2][4];
#pragma unroll
            for (int mq = 0; mq < 2; ++mq)
#pragma unroll
                for (int t = 0; t < 4; ++t) s[mq][t] = (f32x4){0.f, 0.f, 0.f, 0.f};
            __builtin_amdgcn_s_setprio(1);
#pragma unroll
            for (int t = 0; t < 4; ++t) {
                int row = t * 16 + l16;
                int swz = (row & 7) << 4;
                bf16x8 bk0 = *(const bf16x8*)(Ks[cur] + ((row * 128 + ((16 * lg) ^ swz)) >> 1));
                bf16x8 bk1 = *(const bf16x8*)(Ks[cur] + ((row * 128 + ((64 + 16 * lg) ^ swz)) >> 1));
#pragma unroll
                for (int mq = 0; mq < 2; ++mq) {
                    s[mq][t] = __builtin_amdgcn_mfma_f32_16x16x32_bf16(aq[mq][0], bk0, s[mq][t], 0, 0, 0);
                    s[mq][t] = __builtin_amdgcn_mfma_f32_16x16x32_bf16(aq[mq][1], bk1, s[mq][t], 0, 0, 0);
                }
            }
            __builtin_amdgcn_s_setprio(0);

            // ---- max-free softmax + P -> LDS ----
            const bool diag = (kbase + 63 > q0w);
            if (diag) { SOFTMAX_BODY(1) } else { SOFTMAX_BODY(0) }

            // ---- PV: O[32 q][64 d] += P @ V ----
            bf16x8 bv[2][4];
#pragma unroll
            for (int kst = 0; kst < 2; ++kst)
#pragma unroll
                for (int ct = 0; ct < 4; ++ct) {
                    int d = ct * 16 + l16;
                    bv[kst][ct] = *(const bf16x8*)(Vt[cur] + ((d * 128 + ((64 * kst + 16 * lg) ^ ((d & 7) << 4))) >> 1));
                }
            __builtin_amdgcn_s_setprio(1);
#pragma unroll
            for (int mq = 0; mq < 2; ++mq) {
                int rowm = mq * 16 + l16;
                int swz = (rowm & 7) << 4;
                bf16x8 ap0 = *(const bf16x8*)(&Pl[wave][(rowm * 128 + ((16 * lg) ^ swz)) >> 1]);
                bf16x8 ap1 = *(const bf16x8*)(&Pl[wave][(rowm * 128 + ((64 + 16 * lg) ^ swz)) >> 1]);
#pragma unroll
                for (int ct = 0; ct < 4; ++ct) {
                    o[mq][ct] = __builtin_amdgcn_mfma_f32_16x16x32_bf16(ap0, bv[0][ct], o[mq][ct], 0, 0, 0);
                    o[mq][ct] = __builtin_amdgcn_mfma_f32_16x16x32_bf16(ap1, bv[1][ct], o[mq][ct], 0, 0, 0);
                }
            }
            __builtin_amdgcn_s_setprio(0);
        }

        if (more) { WRITE_V(nxt, nv0); }   // vmcnt wait lands here (late)
        __syncthreads();                    // drains own async K + V writes
        cur = nxt;
    }

    // ---- epilogue: reduce l across the 16 k-lanes, normalize, store ----
#pragma unroll
    for (int mq = 0; mq < 2; ++mq)
#pragma unroll
        for (int r = 0; r < 4; ++r) {
            float l = lrow[mq][r];
            l += __shfl_xor(l, 1);
            l += __shfl_xor(l, 2);
            l += __shfl_xor(l, 4);
            l += __shfl_xor(l, 8);
            float inv = 1.f / l;
            size_t zr = ((size_t)b * 2048 + q0w + mq * 16 + lg * 4 + r) * 1024 + h * 64;
#pragma unroll
            for (int ct = 0; ct < 4; ++ct)
                Z[zr + ct * 16 + l16] = f2bf(o[mq][ct][r] * inv);
        }
#undef STAGE_K
#undef LOAD_V
#undef WRITE_V
#undef SOFTMAX_BODY
}

// ---------------------------------------------------------------------------
extern "C" void kernel_launch(void* const* d_in, const int* in_sizes, int n_in,
                              void* d_out, int out_size, void* d_ws, size_t ws_size,
                              hipStream_t stream)
{
    const float* X  = (const float*)d_in[0];
    const float* Wq = (const float*)d_in[1];
    const float* Wk = (const float*)d_in[2];
    const float* Wv = (const float*)d_in[3];
    const float* Wo = (const float*)d_in[4];
    const float* bo = (const float*)d_in[5];
    const float* W1 = (const float*)d_in[6];
    const float* b1 = (const float*)d_in[7];
    const float* W2 = (const float*)d_in[8];
    const float* b2 = (const float*)d_in[9];
    const float* g1 = (const float*)d_in[10];
    const float* s1 = (const float*)d_in[11];
    const float* g2 = (const float*)d_in[12];
    const float* s2 = (const float*)d_in[13];
    float* out = (float*)d_out;

    uint8_t* ws = (uint8_t*)d_ws;
    const size_t MB = 1024 * 1024;
    u16* Wqkvt = (u16*)(ws + 0 * MB);   // [3072][1024] bf16 (Q,K,V stacked)
    u16* Wot   = (u16*)(ws + 6 * MB);   // [1024][1024]
    u16* W1t   = (u16*)(ws + 8 * MB);   // [4096][1024]
    u16* W2t   = (u16*)(ws + 16 * MB);  // [1024][4096]
    u16* Yb    = (u16*)(ws + 24 * MB);  // [8192][1024] LN1 out
    u16* QKVb  = (u16*)(ws + 40 * MB);  // [8192][3072]
    u16* Zb    = (u16*)(ws + 24 * MB);  // reuse Yb (dead after QKV gemm)
    u16* Y2b   = (u16*)(ws + 40 * MB);  // reuse QKVb (dead after attention)
    u16* Hb    = (u16*)(ws + 56 * MB);  // [8192][4096]
    u16* Pk    = (u16*)(ws + 24 * MB);  // split-K partials [2][8192][1024] bf16
                                        // (24-56 MB: Zb+Y2b, dead by step 8)

    // 1) weight prep (single fused launch, 12288 tiles)
    wtrans_all_kernel<<<12288, 256, 0, stream>>>(Wq, Wk, Wv, Wo, W1, W2,
                                                 Wqkvt, Wot, W1t, W2t);

    // 2) LN1
    ln_kernel<<<8192, 256, 0, stream>>>(X, g1, s1, Yb);

    // 3) fused QKV projection (128^2 kernel; 1536 blocks, balanced)
    gemm_kernel<1, 0, 0, 0><<<dim3(24, 64), 256, 0, stream>>>(Yb, Wqkvt, nullptr, nullptr, QKVb, 8192, 3072, 1024);

    // 4) attention (QBLK=256, 8 waves, CU-balanced grid 64x8)
    attn_kernel<<<dim3(64, 8), 512, 0, stream>>>(QKVb, Zb);

    // 5) Wo projection + bo + shortcut X -> X1 (fp32 in d_out)
    gemm_kernel<0, 1, 1, 0><<<dim3(8, 64), 256, 0, stream>>>(Zb, Wot, bo, X, out, 8192, 1024, 1024);

    // 6) LN2
    ln_kernel<<<8192, 256, 0, stream>>>(out, g2, s2, Y2b);

    // 7) FFN up + gelu (8-phase 256^2; grid 16x32 = 512 blocks, balanced)
    gemm8p_kernel<1, 1, 1><<<dim3(16, 32), 512, 0, stream>>>(
        Y2b, W1t, b1, Hb, 8192, 4096, 1024, 1024, 32, 0, 0);

    // 8) FFN down, split-K=2 on the 8-phase kernel: grid (4, 64) = 256 blocks
    //    (full chip, one round); ks = y/32 selects K-half (koff=2048) and
    //    partial buffer (coff = 8192*1024). Partials bf16 into dead ws.
    gemm8p_kernel<1, 0, 0><<<dim3(4, 64), 512, 0, stream>>>(
        Hb, W2t, nullptr, Pk, 8192, 1024, 2048, 4096, 32, 2048, (size_t)8192 * 1024);

    // 8b) combine: out += P0 + P1 + b2 (in-place on d_out, element-wise)
    combine_kernel<<<8192, 256, 0, stream>>>(Pk, Pk + (size_t)8192 * 1024, b2, out);
}

// Round 15
// 376.081 us; speedup vs baseline: 1.0973x; 1.0135x over previous
//
#include <hip/hip_runtime.h>
#include <cstdint>
#include <cstddef>

#define DEV static __device__ __forceinline__

typedef __bf16 bf16x8 __attribute__((ext_vector_type(8)));
typedef float f32x4 __attribute__((ext_vector_type(4)));
typedef unsigned short u16x8 __attribute__((ext_vector_type(8)));
typedef unsigned short u16;

DEV u16 f2bf(float f) { __bf16 b = (__bf16)f; return __builtin_bit_cast(u16, b); }
DEV float bf2f(u16 u) { unsigned v = (unsigned)u << 16; return __builtin_bit_cast(float, v); }

DEV void async_cp16(const void* g, void* l) {
    __builtin_amdgcn_global_load_lds(
        (const __attribute__((address_space(1))) void*)g,
        (__attribute__((address_space(3))) void*)l, 16, 0, 0);
}

DEV void wait_vm6() { asm volatile("s_waitcnt vmcnt(6)" ::: "memory"); }
DEV void wait_vm4() { asm volatile("s_waitcnt vmcnt(4)" ::: "memory"); }
DEV void wait_vm0() { asm volatile("s_waitcnt vmcnt(0)" ::: "memory"); }

// gelu with module's custom 0.04715 constant; overflow-safe tanh
DEV float gelu_fn(float x) {
    const float c = 0.7978845608028654f; // sqrt(2/pi)
    float t = c * (x + 0.04715f * x * x * x);
    float e = __expf(2.f * t);
    float th = 1.f - 2.f / (e + 1.f); // tanh(t), safe at +-inf
    return 0.5f * x * (1.f + th);
}

// ------------- fused weight transpose+cast: all 6 weights, 1 launch --------
__global__ __launch_bounds__(256) void wtrans_all_kernel(
    const float* __restrict__ Wq, const float* __restrict__ Wk,
    const float* __restrict__ Wv, const float* __restrict__ Wo,
    const float* __restrict__ W1, const float* __restrict__ W2,
    u16* __restrict__ Wqkvt, u16* __restrict__ Wot,
    u16* __restrict__ W1t, u16* __restrict__ W2t)
{
    const int bid = blockIdx.x;
    const float* W;
    u16* Wt;
    int K, N, nx, loc;
    if (bid < 4096) {
        loc = bid & 1023;
        const int wsel = bid >> 10;
        W = (wsel == 0) ? Wq : (wsel == 1) ? Wk : (wsel == 2) ? Wv : Wo;
        Wt = (wsel == 3) ? Wot : (Wqkvt + (size_t)wsel * 1024 * 1024);
        K = 1024; N = 1024; nx = 32;
    } else if (bid < 8192) {
        loc = bid - 4096; W = W1; Wt = W1t; K = 1024; N = 4096; nx = 128;
    } else {
        loc = bid - 8192; W = W2; Wt = W2t; K = 4096; N = 1024; nx = 32;
    }
    const int n0 = (loc % nx) * 32, k0 = (loc / nx) * 32;

    __shared__ float t[32][33];
    const int tx = threadIdx.x & 31, ty = threadIdx.x >> 5; // 32 x 8
#pragma unroll
    for (int i = 0; i < 4; ++i)
        t[ty + i * 8][tx] = W[(size_t)(k0 + ty + i * 8) * N + n0 + tx];
    __syncthreads();
#pragma unroll
    for (int i = 0; i < 4; ++i)
        Wt[(size_t)(n0 + ty + i * 8) * K + k0 + tx] = f2bf(t[tx][ty + i * 8]);
}

// ---------------- LayerNorm: f32 [rows][1024] -> bf16 ----------------------
__global__ __launch_bounds__(256) void ln_kernel(
    const float* __restrict__ X, const float* __restrict__ g,
    const float* __restrict__ sh, u16* __restrict__ Y)
{
    int row = blockIdx.x;
    const float4* xr = (const float4*)(X + (size_t)row * 1024);
    float4 x = xr[threadIdx.x];
    float s = x.x + x.y + x.z + x.w;
    float ss = x.x * x.x + x.y * x.y + x.z * x.z + x.w * x.w;
#pragma unroll
    for (int off = 32; off >= 1; off >>= 1) {
        s += __shfl_xor(s, off);
        ss += __shfl_xor(ss, off);
    }
    __shared__ float ps[4], pss[4];
    int wave = threadIdx.x >> 6, lane = threadIdx.x & 63;
    if (lane == 0) { ps[wave] = s; pss[wave] = ss; }
    __syncthreads();
    s = ps[0] + ps[1] + ps[2] + ps[3];
    ss = pss[0] + pss[1] + pss[2] + pss[3];
    float mean = s * (1.f / 1024.f);
    float var = ss * (1.f / 1024.f) - mean * mean;
    float rstd = rsqrtf(var + 1e-5f);
    int c = threadIdx.x * 4;
    ushort4 o;
    o.x = f2bf((x.x - mean) * rstd * g[c + 0] + sh[c + 0]);
    o.y = f2bf((x.y - mean) * rstd * g[c + 1] + sh[c + 1]);
    o.z = f2bf((x.z - mean) * rstd * g[c + 2] + sh[c + 2]);
    o.w = f2bf((x.w - mean) * rstd * g[c + 3] + sh[c + 3]);
    ((ushort4*)(Y + (size_t)row * 1024))[threadIdx.x] = o;
}

// ---------------- FFN-down split-K combine: out += P0 + P1 + b2 ------------
__global__ __launch_bounds__(256) void combine_kernel(
    const u16* __restrict__ P0, const u16* __restrict__ P1,
    const float* __restrict__ b2, float* __restrict__ out)
{
    const size_t row = blockIdx.x;
    const int c = threadIdx.x * 4;
    const size_t off = row * 1024 + c;
    ushort4 a = *(const ushort4*)(P0 + off);
    ushort4 b = *(const ushort4*)(P1 + off);
    float4 o = *(float4*)(out + off);
    o.x += bf2f(a.x) + bf2f(b.x) + b2[c + 0];
    o.y += bf2f(a.y) + bf2f(b.y) + b2[c + 1];
    o.z += bf2f(a.z) + bf2f(b.z) + b2[c + 2];
    o.w += bf2f(a.w) + bf2f(b.w) + b2[c + 3];
    *(float4*)(out + off) = o;
}

// ---------------- GEMM 128x128 (R12-proven): C = A @ Bt^T ------------------
// BK=32, 4 waves, 3-deep staging + counted vmcnt(4), single raw barrier per
// K-step (never drains the prefetch pipeline to 0 mid-loop).
template <int OUT_BF16, int HAS_BIAS, int HAS_RES, int ACT_GELU>
__global__ __launch_bounds__(256) void gemm_kernel(
    const u16* __restrict__ A, const u16* __restrict__ Bt,
    const float* __restrict__ bias, const float* __restrict__ res,
    void* __restrict__ Cout, int M, int N, int K)
{
    __shared__ u16 As[3][128 * 32];
    __shared__ u16 Bs[3][128 * 32];
    const int tid = threadIdx.x;
    const int lane = tid & 63, wave = tid >> 6;
    const int wm = wave >> 1, wn = wave & 1;
    const int l16 = lane & 15, lg = lane >> 4;
    const int rowBase = blockIdx.y * 128;
    const int colBase = blockIdx.x * 128;

    f32x4 acc[4][4];
#pragma unroll
    for (int m = 0; m < 4; ++m)
#pragma unroll
        for (int n = 0; n < 4; ++n) acc[m][n] = (f32x4){0.f, 0.f, 0.f, 0.f};

#define GSTAGE(SB, KT)                                                        \
    {                                                                         \
        _Pragma("unroll")                                                     \
        for (int i_ = 0; i_ < 2; ++i_) {                                      \
            int eo = tid * 8 + i_ * 2048;                                     \
            int r_ = eo >> 5, c_ = eo & 31;                                   \
            async_cp16(A + (size_t)(rowBase + r_) * K + (KT) + c_, As[SB] + eo); \
            async_cp16(Bt + (size_t)(colBase + r_) * K + (KT) + c_, Bs[SB] + eo); \
        }                                                                     \
    }

    const int nt = K >> 5;
    GSTAGE(0, 0);
    GSTAGE(1, 32);
    wait_vm4();
    __builtin_amdgcn_s_barrier();
    __builtin_amdgcn_sched_barrier(0);

    int cur = 0, stg = 2;
    for (int t = 0; t < nt; ++t) {
        const bool more = (t + 2 < nt);
        if (more) GSTAGE(stg, (t + 2) * 32);

        bf16x8 af[4], bfr[4];
#pragma unroll
        for (int m = 0; m < 4; ++m)
            af[m] = *(const bf16x8*)(As[cur] + (wm * 64 + m * 16 + l16) * 32 + lg * 8);
#pragma unroll
        for (int n = 0; n < 4; ++n)
            bfr[n] = *(const bf16x8*)(Bs[cur] + (wn * 64 + n * 16 + l16) * 32 + lg * 8);
#pragma unroll
        for (int m = 0; m < 4; ++m)
#pragma unroll
            for (int n = 0; n < 4; ++n)
                acc[m][n] = __builtin_amdgcn_mfma_f32_16x16x32_bf16(
                    af[m], bfr[n], acc[m][n], 0, 0, 0);

        if (more) wait_vm4(); else wait_vm0();
        __builtin_amdgcn_s_barrier();
        __builtin_amdgcn_sched_barrier(0);
        cur = (cur == 2) ? 0 : cur + 1;
        stg = (stg == 2) ? 0 : stg + 1;
    }
#undef GSTAGE

#pragma unroll
    for (int m = 0; m < 4; ++m) {
#pragma unroll
        for (int n = 0; n < 4; ++n) {
            int gr0 = rowBase + wm * 64 + m * 16 + lg * 4;
            int gc = colBase + wn * 64 + n * 16 + l16;
            float bv = HAS_BIAS ? bias[gc] : 0.f;
#pragma unroll
            for (int r = 0; r < 4; ++r) {
                float v = acc[m][n][r] + bv;
                if (ACT_GELU) v = gelu_fn(v);
                if (HAS_RES) v += res[(size_t)(gr0 + r) * N + gc];
                if (OUT_BF16)
                    ((u16*)Cout)[(size_t)(gr0 + r) * N + gc] = f2bf(v);
                else
                    ((float*)Cout)[(size_t)(gr0 + r) * N + gc] = v;
            }
        }
    }
}

// ---------------- GEMM 256x256, BK=64, 8 waves, 8-phase --------------------
// R15: ROWCHUNK selects the XCD-chunk axis. ROWCHUNK=0 (R8-proven): each
// XCD's contiguous work range shares B col-panels, streams all of A
// (L2-miss model: 8*|A|+|B|). ROWCHUNK=1: each XCD owns a few A row-tiles
// (L2-resident) and streams B once (model: |A|+8*|B|) — wins when A is the
// big operand (FFN-up: 135MB measured vs 136 predicted -> 80 predicted).
template <int OUT_BF16, int HAS_BIAS, int ACT_GELU, int ROWCHUNK>
__global__ __launch_bounds__(512, 2) void gemm8p_kernel(
    const u16* __restrict__ A, const u16* __restrict__ Bt,
    const float* __restrict__ bias, void* __restrict__ Cout,
    int M, int N, int K, int ldk, int rowTiles, int koff, size_t coff)
{
    __shared__ u16 As[2][256 * 64];
    __shared__ u16 Bs[2][256 * 64];
    const int tid = threadIdx.x;
    const int lane = tid & 63, wave = tid >> 6;
    const int wm = wave >> 2, wn = wave & 3;     // 2 x 4 wave grid
    const int l16 = lane & 15, lg = lane >> 4;

    const int gx = gridDim.x, gy = gridDim.y;
    const int nwg = gx * gy;
    const int orig = (int)blockIdx.y * gx + (int)blockIdx.x;
    const int work = (orig & 7) * (nwg >> 3) + (orig >> 3);
    int colSel, wy;
    if (ROWCHUNK) { colSel = work % gx; wy = work / gx; }
    else          { colSel = work / gy; wy = work % gy; }
    const int colBase = colSel * 256;
    const int rowBase = (wy % rowTiles) * 256;
    const int ks = wy / rowTiles;
    A += (size_t)ks * koff;
    Bt += (size_t)ks * koff;

    f32x4 acc[8][4];
#pragma unroll
    for (int m = 0; m < 8; ++m)
#pragma unroll
        for (int n = 0; n < 4; ++n) acc[m][n] = (f32x4){0.f, 0.f, 0.f, 0.f};

#define STRIP(SB, KT, S)                                                      \
    {                                                                         \
        int tl_ = tid & 255, hf_ = tid >> 8;                                  \
        int r_ = hf_ * 128 + (S) * 32 + (tl_ >> 3);                           \
        int gl_ = (tl_ & 7) ^ (r_ & 7);                                       \
        int dst_ = r_ * 64 + (tl_ & 7) * 8;                                   \
        async_cp16(A + (size_t)(rowBase + r_) * ldk + (KT) + gl_ * 8, As[SB] + dst_); \
        async_cp16(Bt + (size_t)(colBase + r_) * ldk + (KT) + gl_ * 8, Bs[SB] + dst_); \
    }
#define FRAG_OFF(row, G) ((row) * 64 + (((G) ^ ((row) & 7)) * 8))

#define PHASE(BUF, QUAD, LOADB, STAGE, WAITN)                                 \
    {                                                                         \
        __builtin_amdgcn_sched_barrier(0);                                    \
        if (LOADB) {                                                          \
            _Pragma("unroll")                                                 \
            for (int nf = 0; nf < 4; ++nf) {                                  \
                int row = wn * 64 + nf * 16 + l16;                            \
                _Pragma("unroll")                                             \
                for (int ks_ = 0; ks_ < 2; ++ks_)                             \
                    bfr[nf][ks_] = *(const bf16x8*)(Bs[BUF] + FRAG_OFF(row, lg + ks_ * 4)); \
            }                                                                 \
        }                                                                     \
        bf16x8 af[2][2];                                                      \
        _Pragma("unroll")                                                     \
        for (int mi = 0; mi < 2; ++mi) {                                      \
            int row = wm * 128 + (QUAD) * 32 + mi * 16 + l16;                 \
            _Pragma("unroll")                                                 \
            for (int ks_ = 0; ks_ < 2; ++ks_)                                 \
                af[mi][ks_] = *(const bf16x8*)(As[BUF] + FRAG_OFF(row, lg + ks_ * 4)); \
        }                                                                     \
        STAGE;                                                                \
        __builtin_amdgcn_sched_barrier(0);                                    \
        __builtin_amdgcn_s_barrier();                                         \
        __builtin_amdgcn_s_setprio(1);                                        \
        _Pragma("unroll")                                                     \
        for (int mi = 0; mi < 2; ++mi)                                        \
            _Pragma("unroll")                                                 \
            for (int nf = 0; nf < 4; ++nf)                                    \
                _Pragma("unroll")                                             \
                for (int ks_ = 0; ks_ < 2; ++ks_)                             \
                    acc[(QUAD) * 2 + mi][nf] =                                \
                        __builtin_amdgcn_mfma_f32_16x16x32_bf16(              \
                            af[mi][ks_], bfr[nf][ks_], acc[(QUAD) * 2 + mi][nf], 0, 0, 0); \
        __builtin_amdgcn_s_setprio(0);                                        \
        __builtin_amdgcn_sched_barrier(0);                                    \
        WAITN;                                                                \
        __builtin_amdgcn_s_barrier();                                         \
    }

    const int nt = K >> 6;
    const int half = nt >> 1;

    STRIP(0, 0, 0); STRIP(0, 0, 1); STRIP(0, 0, 2); STRIP(0, 0, 3);
    STRIP(1, 64, 0); STRIP(1, 64, 1); STRIP(1, 64, 2);
    wait_vm6();
    __builtin_amdgcn_s_barrier();
    __builtin_amdgcn_sched_barrier(0);

    for (int it = 0; it < half; ++it) {
        const int kt1 = (it * 2 + 1) << 6;
        const int kt2 = (it * 2 + 2) << 6;
        const int kt3 = (it * 2 + 3) << 6;
        const bool more = (it + 1 < half);
        bf16x8 bfr[4][2];
        PHASE(0, 0, 1, STRIP(1, kt1, 3), ((void)0));
        PHASE(0, 1, 0, if (more) STRIP(0, kt2, 0), ((void)0));
        PHASE(0, 2, 0, if (more) STRIP(0, kt2, 1), ((void)0));
        PHASE(0, 3, 0, if (more) STRIP(0, kt2, 2),
              if (more) wait_vm6(); else wait_vm0());
        PHASE(1, 0, 1, if (more) STRIP(0, kt2, 3), ((void)0));
        PHASE(1, 1, 0, if (more) STRIP(1, kt3, 0), ((void)0));
        PHASE(1, 2, 0, if (more) STRIP(1, kt3, 1), ((void)0));
        PHASE(1, 3, 0, if (more) STRIP(1, kt3, 2),
              if (more) wait_vm6(); else wait_vm0());
    }
#undef STRIP
#undef FRAG_OFF
#undef PHASE

#pragma unroll
    for (int mf = 0; mf < 8; ++mf) {
#pragma unroll
        for (int nf = 0; nf < 4; ++nf) {
            int gr0 = rowBase + wm * 128 + mf * 16 + lg * 4;
            int gc = colBase + wn * 64 + nf * 16 + l16;
            float bv = HAS_BIAS ? bias[gc] : 0.f;
#pragma unroll
            for (int r = 0; r < 4; ++r) {
                float v = acc[mf][nf][r] + bv;
                if (ACT_GELU) v = gelu_fn(v);
                if (OUT_BF16)
                    ((u16*)Cout)[(size_t)ks * coff + (size_t)(gr0 + r) * N + gc] = f2bf(v);
                else
                    ((float*)Cout)[(size_t)ks * coff + (size_t)(gr0 + r) * N + gc] = v;
            }
        }
    }
}

// ---------------- causal flash attention (R12-proven: balanced grid) -------
__global__ __launch_bounds__(512) void attn_kernel(
    const u16* __restrict__ QKV, u16* __restrict__ Z)
{
    __shared__ u16 Ks[2][64 * 64];
    __shared__ u16 Vt[2][64 * 64];
    __shared__ u16 Pl[8][32 * 64];

    const int bh = blockIdx.x;               // 0..63
    const int b = bh >> 4, h = bh & 15;
    const int g = blockIdx.y;                // 0..7
    const int qt = (g < 4) ? (7 - g) : (g - 4);  // complementary at stride 256
    const int tid = threadIdx.x;
    const int wave = tid >> 6, lane = tid & 63;
    const int l16 = lane & 15, lg = lane >> 4;

    const size_t baseQ = (size_t)b * 2048 * 3072 + (size_t)h * 64;
    const size_t baseK = baseQ + 1024;
    const size_t baseV = baseQ + 2048;

    const int q0w = qt * 256 + wave * 32;

    // Q fragments, pre-scaled by 1/sqrt(64)=0.125 (exact pow2)
    bf16x8 aq[2][2];
#pragma unroll
    for (int mq = 0; mq < 2; ++mq) {
        const u16* qp = QKV + baseQ + (size_t)(q0w + mq * 16 + l16) * 3072;
#pragma unroll
        for (int hf = 0; hf < 2; ++hf) {
            bf16x8 v = *(const bf16x8*)(qp + hf * 32 + lg * 8);
#pragma unroll
            for (int j = 0; j < 8; ++j) v[j] = (__bf16)((float)v[j] * 0.125f);
            aq[mq][hf] = v;
        }
    }

    f32x4 o[2][4];
    float lrow[2][4];
#pragma unroll
    for (int mq = 0; mq < 2; ++mq)
#pragma unroll
        for (int i = 0; i < 4; ++i) {
            o[mq][i] = (f32x4){0.f, 0.f, 0.f, 0.f};
            lrow[mq][i] = 0.f;
        }

    const int nch = 4 * qt + 4;

    // 512 threads: one cp16 each covers the 64x64 K tile (xor-swizzled rows)
#define STAGE_K(BUF, KB)                                                      \
    {                                                                         \
        int n = tid;                                                          \
        int r = n >> 3;                                                       \
        int lb = ((n & 7) * 16) ^ ((r & 7) << 4);                             \
        async_cp16(QKV + baseK + (size_t)((KB) + r) * 3072 + (lb >> 1),       \
                   Ks[BUF] + n * 8);                                          \
    }
    // wave w owns d rows w*8..w*8+7; lane = k (64 lanes)
#define LOAD_V(KB, V0)                                                        \
    {                                                                         \
        const u16* vp = QKV + baseV + (size_t)((KB) + lane) * 3072;           \
        V0 = *(const u16x8*)(vp + wave * 8);                                  \
    }
#define WRITE_V(BUF, V0)                                                      \
    {                                                                         \
        _Pragma("unroll")                                                     \
        for (int j = 0; j < 8; ++j) {                                         \
            int d = wave * 8 + j;                                             \
            int byt = (d * 128 + lane * 2) ^ ((d & 7) << 4);                  \
            Vt[BUF][byt >> 1] = V0[j];                                        \
        }                                                                     \
    }
#define SOFTMAX_BODY(DIAG)                                                    \
    _Pragma("unroll")                                                         \
    for (int mq = 0; mq < 2; ++mq) {                                          \
        _Pragma("unroll")                                                     \
        for (int r = 0; r < 4; ++r) {                                         \
            float sv0 = s[mq][0][r];                                          \
            float sv1 = s[mq][1][r];                                          \
            float sv2 = s[mq][2][r];                                          \
            float sv3 = s[mq][3][r];                                          \
            if (DIAG) {                                                       \
                const int q = q0w + mq * 16 + lg * 4 + r;                     \
                if (kbase + 0 + l16 > q)  sv0 = -1e30f;                       \
                if (kbase + 16 + l16 > q) sv1 = -1e30f;                       \
                if (kbase + 32 + l16 > q) sv2 = -1e30f;                       \
                if (kbase + 48 + l16 > q) sv3 = -1e30f;                       \
            }                                                                 \
            float p0 = __expf(sv0), p1 = __expf(sv1);                         \
            float p2 = __expf(sv2), p3 = __expf(sv3);                         \
            lrow[mq][r] += (p0 + p1) + (p2 + p3);                             \
            int rowm = mq * 16 + lg * 4 + r;                                  \
            int rb = rowm * 128, swz = (rowm & 7) << 4;                       \
            Pl[wave][(rb + ((0  + 2 * l16) ^ swz)) >> 1] = f2bf(p0);          \
            Pl[wave][(rb + ((32 + 2 * l16) ^ swz)) >> 1] = f2bf(p1);          \
            Pl[wave][(rb + ((64 + 2 * l16) ^ swz)) >> 1] = f2bf(p2);          \
            Pl[wave][(rb + ((96 + 2 * l16) ^ swz)) >> 1] = f2bf(p3);          \
        }                                                                     \
    }

    // ---- prologue: stage chunk 0 into buffer 0 ----
    {
        STAGE_K(0, 0);
        u16x8 v0;
        LOAD_V(0, v0);
        WRITE_V(0, v0);
    }
    __syncthreads();

    int cur = 0;
    for (int kc = 0; kc < nch; ++kc) {
        const int kbase = kc * 64;
        const int nxt = cur ^ 1;
        const bool more = (kc + 1 < nch);
        u16x8 nv0;
        if (more) {
            STAGE_K(nxt, kbase + 64);      // async global->LDS, drains at barrier
            LOAD_V(kbase + 64, nv0);       // global->reg, written post-compute
        }

        if (q0w + 31 >= kbase) {
            // ---- QK^T: S[32 q][64 k] ----
            f32x4 s[2][4];
#pragma unroll
            for (int mq = 0; mq < 2; ++mq)
#pragma unroll
                for (int t = 0; t < 4; ++t) s[mq][t] = (f32x4){0.f, 0.f, 0.f, 0.f};
            __builtin_amdgcn_s_setprio(1);
#pragma unroll
            for (int t = 0; t < 4; ++t) {
                int row = t * 16 + l16;
                int swz = (row & 7) << 4;
                bf16x8 bk0 = *(const bf16x8*)(Ks[cur] + ((row * 128 + ((16 * lg) ^ swz)) >> 1));
                bf16x8 bk1 = *(const bf16x8*)(Ks[cur] + ((row * 128 + ((64 + 16 * lg) ^ swz)) >> 1));
#pragma unroll
                for (int mq = 0; mq < 2; ++mq) {
                    s[mq][t] = __builtin_amdgcn_mfma_f32_16x16x32_bf16(aq[mq][0], bk0, s[mq][t], 0, 0, 0);
                    s[mq][t] = __builtin_amdgcn_mfma_f32_16x16x32_bf16(aq[mq][1], bk1, s[mq][t], 0, 0, 0);
                }
            }
            __builtin_amdgcn_s_setprio(0);

            // ---- max-free softmax + P -> LDS ----
            const bool diag = (kbase + 63 > q0w);
            if (diag) { SOFTMAX_BODY(1) } else { SOFTMAX_BODY(0) }

            // ---- PV: O[32 q][64 d] += P @ V ----
            bf16x8 bv[2][4];
#pragma unroll
            for (int kst = 0; kst < 2; ++kst)
#pragma unroll
                for (int ct = 0; ct < 4; ++ct) {
                    int d = ct * 16 + l16;
                    bv[kst][ct] = *(const bf16x8*)(Vt[cur] + ((d * 128 + ((64 * kst + 16 * lg) ^ ((d & 7) << 4))) >> 1));
                }
            __builtin_amdgcn_s_setprio(1);
#pragma unroll
            for (int mq = 0; mq < 2; ++mq) {
                int rowm = mq * 16 + l16;
                int swz = (rowm & 7) << 4;
                bf16x8 ap0 = *(const bf16x8*)(&Pl[wave][(rowm * 128 + ((16 * lg) ^ swz)) >> 1]);
                bf16x8 ap1 = *(const bf16x8*)(&Pl[wave][(rowm * 128 + ((64 + 16 * lg) ^ swz)) >> 1]);
#pragma unroll
                for (int ct = 0; ct < 4; ++ct) {
                    o[mq][ct] = __builtin_amdgcn_mfma_f32_16x16x32_bf16(ap0, bv[0][ct], o[mq][ct], 0, 0, 0);
                    o[mq][ct] = __builtin_amdgcn_mfma_f32_16x16x32_bf16(ap1, bv[1][ct], o[mq][ct], 0, 0, 0);
                }
            }
            __builtin_amdgcn_s_setprio(0);
        }

        if (more) { WRITE_V(nxt, nv0); }   // vmcnt wait lands here (late)
        __syncthreads();                    // drains own async K + V writes
        cur = nxt;
    }

    // ---- epilogue: reduce l across the 16 k-lanes, normalize, store ----
#pragma unroll
    for (int mq = 0; mq < 2; ++mq)
#pragma unroll
        for (int r = 0; r < 4; ++r) {
            float l = lrow[mq][r];
            l += __shfl_xor(l, 1);
            l += __shfl_xor(l, 2);
            l += __shfl_xor(l, 4);
            l += __shfl_xor(l, 8);
            float inv = 1.f / l;
            size_t zr = ((size_t)b * 2048 + q0w + mq * 16 + lg * 4 + r) * 1024 + h * 64;
#pragma unroll
            for (int ct = 0; ct < 4; ++ct)
                Z[zr + ct * 16 + l16] = f2bf(o[mq][ct][r] * inv);
        }
#undef STAGE_K
#undef LOAD_V
#undef WRITE_V
#undef SOFTMAX_BODY
}

// ---------------------------------------------------------------------------
extern "C" void kernel_launch(void* const* d_in, const int* in_sizes, int n_in,
                              void* d_out, int out_size, void* d_ws, size_t ws_size,
                              hipStream_t stream)
{
    const float* X  = (const float*)d_in[0];
    const float* Wq = (const float*)d_in[1];
    const float* Wk = (const float*)d_in[2];
    const float* Wv = (const float*)d_in[3];
    const float* Wo = (const float*)d_in[4];
    const float* bo = (const float*)d_in[5];
    const float* W1 = (const float*)d_in[6];
    const float* b1 = (const float*)d_in[7];
    const float* W2 = (const float*)d_in[8];
    const float* b2 = (const float*)d_in[9];
    const float* g1 = (const float*)d_in[10];
    const float* s1 = (const float*)d_in[11];
    const float* g2 = (const float*)d_in[12];
    const float* s2 = (const float*)d_in[13];
    float* out = (float*)d_out;

    uint8_t* ws = (uint8_t*)d_ws;
    const size_t MB = 1024 * 1024;
    u16* Wqkvt = (u16*)(ws + 0 * MB);   // [3072][1024] bf16 (Q,K,V stacked)
    u16* Wot   = (u16*)(ws + 6 * MB);   // [1024][1024]
    u16* W1t   = (u16*)(ws + 8 * MB);   // [4096][1024]
    u16* W2t   = (u16*)(ws + 16 * MB);  // [1024][4096]
    u16* Yb    = (u16*)(ws + 24 * MB);  // [8192][1024] LN1 out
    u16* QKVb  = (u16*)(ws + 40 * MB);  // [8192][3072]
    u16* Zb    = (u16*)(ws + 24 * MB);  // reuse Yb (dead after QKV gemm)
    u16* Y2b   = (u16*)(ws + 40 * MB);  // reuse QKVb (dead after attention)
    u16* Hb    = (u16*)(ws + 56 * MB);  // [8192][4096]
    u16* Pk    = (u16*)(ws + 24 * MB);  // split-K partials [2][8192][1024] bf16
                                        // (24-56 MB: Zb+Y2b, dead by step 8)

    // 1) weight prep (single fused launch, 12288 tiles)
    wtrans_all_kernel<<<12288, 256, 0, stream>>>(Wq, Wk, Wv, Wo, W1, W2,
                                                 Wqkvt, Wot, W1t, W2t);

    // 2) LN1
    ln_kernel<<<8192, 256, 0, stream>>>(X, g1, s1, Yb);

    // 3) fused QKV projection (128^2 kernel; 1536 blocks, balanced)
    gemm_kernel<1, 0, 0, 0><<<dim3(24, 64), 256, 0, stream>>>(Yb, Wqkvt, nullptr, nullptr, QKVb, 8192, 3072, 1024);

    // 4) attention (QBLK=256, 8 waves, CU-balanced grid 64x8)
    attn_kernel<<<dim3(64, 8), 512, 0, stream>>>(QKVb, Zb);

    // 5) Wo projection + bo + shortcut X -> X1 (fp32 in d_out)
    gemm_kernel<0, 1, 1, 0><<<dim3(8, 64), 256, 0, stream>>>(Zb, Wot, bo, X, out, 8192, 1024, 1024);

    // 6) LN2
    ln_kernel<<<8192, 256, 0, stream>>>(out, g2, s2, Y2b);

    // 7) FFN up + gelu (8-phase; ROWCHUNK: each XCD holds 4 A row-tiles in
    //    L2, streams B once — predicted L2-miss 135 -> ~80 MB)
    gemm8p_kernel<1, 1, 1, 1><<<dim3(16, 32), 512, 0, stream>>>(
        Y2b, W1t, b1, Hb, 8192, 4096, 1024, 1024, 32, 0, 0);

    // 8) FFN down, split-K=2, ROWCHUNK (A=Hb 64MB is the big streamed
    //    operand; row-chunking keeps each XCD's A slice L2-warm)
    gemm8p_kernel<1, 0, 0, 1><<<dim3(4, 64), 512, 0, stream>>>(
        Hb, W2t, nullptr, Pk, 8192, 1024, 2048, 4096, 32, 2048, (size_t)8192 * 1024);

    // 8b) combine: out += P0 + P1 + b2 (in-place on d_out, element-wise)
    combine_kernel<<<8192, 256, 0, stream>>>(Pk, Pk + (size_t)8192 * 1024, b2, out);
}

// Round 16
// 375.700 us; speedup vs baseline: 1.0984x; 1.0010x over previous
//
#include <hip/hip_runtime.h>
#include <cstdint>
#include <cstddef>

#define DEV static __device__ __forceinline__

typedef __bf16 bf16x8 __attribute__((ext_vector_type(8)));
typedef float f32x4 __attribute__((ext_vector_type(4)));
typedef unsigned short u16x8 __attribute__((ext_vector_type(8)));
typedef unsigned short u16;

DEV u16 f2bf(float f) { __bf16 b = (__bf16)f; return __builtin_bit_cast(u16, b); }
DEV float bf2f(u16 u) { unsigned v = (unsigned)u << 16; return __builtin_bit_cast(float, v); }

DEV void async_cp16(const void* g, void* l) {
    __builtin_amdgcn_global_load_lds(
        (const __attribute__((address_space(1))) void*)g,
        (__attribute__((address_space(3))) void*)l, 16, 0, 0);
}

DEV void wait_vm6() { asm volatile("s_waitcnt vmcnt(6)" ::: "memory"); }
DEV void wait_vm4() { asm volatile("s_waitcnt vmcnt(4)" ::: "memory"); }
DEV void wait_vm0() { asm volatile("s_waitcnt vmcnt(0)" ::: "memory"); }

// gelu with module's custom 0.04715 constant; overflow-safe tanh
DEV float gelu_fn(float x) {
    const float c = 0.7978845608028654f; // sqrt(2/pi)
    float t = c * (x + 0.04715f * x * x * x);
    float e = __expf(2.f * t);
    float th = 1.f - 2.f / (e + 1.f); // tanh(t), safe at +-inf
    return 0.5f * x * (1.f + th);
}

// ------------- fused weight transpose+cast: all 6 weights, 1 launch --------
__global__ __launch_bounds__(256) void wtrans_all_kernel(
    const float* __restrict__ Wq, const float* __restrict__ Wk,
    const float* __restrict__ Wv, const float* __restrict__ Wo,
    const float* __restrict__ W1, const float* __restrict__ W2,
    u16* __restrict__ Wqkvt, u16* __restrict__ Wot,
    u16* __restrict__ W1t, u16* __restrict__ W2t)
{
    const int bid = blockIdx.x;
    const float* W;
    u16* Wt;
    int K, N, nx, loc;
    if (bid < 4096) {
        loc = bid & 1023;
        const int wsel = bid >> 10;
        W = (wsel == 0) ? Wq : (wsel == 1) ? Wk : (wsel == 2) ? Wv : Wo;
        Wt = (wsel == 3) ? Wot : (Wqkvt + (size_t)wsel * 1024 * 1024);
        K = 1024; N = 1024; nx = 32;
    } else if (bid < 8192) {
        loc = bid - 4096; W = W1; Wt = W1t; K = 1024; N = 4096; nx = 128;
    } else {
        loc = bid - 8192; W = W2; Wt = W2t; K = 4096; N = 1024; nx = 32;
    }
    const int n0 = (loc % nx) * 32, k0 = (loc / nx) * 32;

    __shared__ float t[32][33];
    const int tx = threadIdx.x & 31, ty = threadIdx.x >> 5; // 32 x 8
#pragma unroll
    for (int i = 0; i < 4; ++i)
        t[ty + i * 8][tx] = W[(size_t)(k0 + ty + i * 8) * N + n0 + tx];
    __syncthreads();
#pragma unroll
    for (int i = 0; i < 4; ++i)
        Wt[(size_t)(n0 + ty + i * 8) * K + k0 + tx] = f2bf(t[tx][ty + i * 8]);
}

// ---------------- LayerNorm: f32 [rows][1024] -> bf16 ----------------------
__global__ __launch_bounds__(256) void ln_kernel(
    const float* __restrict__ X, const float* __restrict__ g,
    const float* __restrict__ sh, u16* __restrict__ Y)
{
    int row = blockIdx.x;
    const float4* xr = (const float4*)(X + (size_t)row * 1024);
    float4 x = xr[threadIdx.x];
    float s = x.x + x.y + x.z + x.w;
    float ss = x.x * x.x + x.y * x.y + x.z * x.z + x.w * x.w;
#pragma unroll
    for (int off = 32; off >= 1; off >>= 1) {
        s += __shfl_xor(s, off);
        ss += __shfl_xor(ss, off);
    }
    __shared__ float ps[4], pss[4];
    int wave = threadIdx.x >> 6, lane = threadIdx.x & 63;
    if (lane == 0) { ps[wave] = s; pss[wave] = ss; }
    __syncthreads();
    s = ps[0] + ps[1] + ps[2] + ps[3];
    ss = pss[0] + pss[1] + pss[2] + pss[3];
    float mean = s * (1.f / 1024.f);
    float var = ss * (1.f / 1024.f) - mean * mean;
    float rstd = rsqrtf(var + 1e-5f);
    int c = threadIdx.x * 4;
    ushort4 o;
    o.x = f2bf((x.x - mean) * rstd * g[c + 0] + sh[c + 0]);
    o.y = f2bf((x.y - mean) * rstd * g[c + 1] + sh[c + 1]);
    o.z = f2bf((x.z - mean) * rstd * g[c + 2] + sh[c + 2]);
    o.w = f2bf((x.w - mean) * rstd * g[c + 3] + sh[c + 3]);
    ((ushort4*)(Y + (size_t)row * 1024))[threadIdx.x] = o;
}

// ---------------- FFN-down split-K combine: out += P0 + P1 + b2 ------------
__global__ __launch_bounds__(256) void combine_kernel(
    const u16* __restrict__ P0, const u16* __restrict__ P1,
    const float* __restrict__ b2, float* __restrict__ out)
{
    const size_t row = blockIdx.x;
    const int c = threadIdx.x * 4;
    const size_t off = row * 1024 + c;
    ushort4 a = *(const ushort4*)(P0 + off);
    ushort4 b = *(const ushort4*)(P1 + off);
    float4 o = *(float4*)(out + off);
    o.x += bf2f(a.x) + bf2f(b.x) + b2[c + 0];
    o.y += bf2f(a.y) + bf2f(b.y) + b2[c + 1];
    o.z += bf2f(a.z) + bf2f(b.z) + b2[c + 2];
    o.w += bf2f(a.w) + bf2f(b.w) + b2[c + 3];
    *(float4*)(out + off) = o;
}

// ---------------- GEMM 128x128 (R12-proven): C = A @ Bt^T ------------------
// BK=32, 4 waves, 3-deep staging + counted vmcnt(4), single raw barrier per
// K-step (never drains the prefetch pipeline to 0 mid-loop).
template <int OUT_BF16, int HAS_BIAS, int HAS_RES, int ACT_GELU>
__global__ __launch_bounds__(256) void gemm_kernel(
    const u16* __restrict__ A, const u16* __restrict__ Bt,
    const float* __restrict__ bias, const float* __restrict__ res,
    void* __restrict__ Cout, int M, int N, int K)
{
    __shared__ u16 As[3][128 * 32];
    __shared__ u16 Bs[3][128 * 32];
    const int tid = threadIdx.x;
    const int lane = tid & 63, wave = tid >> 6;
    const int wm = wave >> 1, wn = wave & 1;
    const int l16 = lane & 15, lg = lane >> 4;
    const int rowBase = blockIdx.y * 128;
    const int colBase = blockIdx.x * 128;

    f32x4 acc[4][4];
#pragma unroll
    for (int m = 0; m < 4; ++m)
#pragma unroll
        for (int n = 0; n < 4; ++n) acc[m][n] = (f32x4){0.f, 0.f, 0.f, 0.f};

#define GSTAGE(SB, KT)                                                        \
    {                                                                         \
        _Pragma("unroll")                                                     \
        for (int i_ = 0; i_ < 2; ++i_) {                                      \
            int eo = tid * 8 + i_ * 2048;                                     \
            int r_ = eo >> 5, c_ = eo & 31;                                   \
            async_cp16(A + (size_t)(rowBase + r_) * K + (KT) + c_, As[SB] + eo); \
            async_cp16(Bt + (size_t)(colBase + r_) * K + (KT) + c_, Bs[SB] + eo); \
        }                                                                     \
    }

    const int nt = K >> 5;
    GSTAGE(0, 0);
    GSTAGE(1, 32);
    wait_vm4();
    __builtin_amdgcn_s_barrier();
    __builtin_amdgcn_sched_barrier(0);

    int cur = 0, stg = 2;
    for (int t = 0; t < nt; ++t) {
        const bool more = (t + 2 < nt);
        if (more) GSTAGE(stg, (t + 2) * 32);

        bf16x8 af[4], bfr[4];
#pragma unroll
        for (int m = 0; m < 4; ++m)
            af[m] = *(const bf16x8*)(As[cur] + (wm * 64 + m * 16 + l16) * 32 + lg * 8);
#pragma unroll
        for (int n = 0; n < 4; ++n)
            bfr[n] = *(const bf16x8*)(Bs[cur] + (wn * 64 + n * 16 + l16) * 32 + lg * 8);
#pragma unroll
        for (int m = 0; m < 4; ++m)
#pragma unroll
            for (int n = 0; n < 4; ++n)
                acc[m][n] = __builtin_amdgcn_mfma_f32_16x16x32_bf16(
                    af[m], bfr[n], acc[m][n], 0, 0, 0);

        if (more) wait_vm4(); else wait_vm0();
        __builtin_amdgcn_s_barrier();
        __builtin_amdgcn_sched_barrier(0);
        cur = (cur == 2) ? 0 : cur + 1;
        stg = (stg == 2) ? 0 : stg + 1;
    }
#undef GSTAGE

#pragma unroll
    for (int m = 0; m < 4; ++m) {
#pragma unroll
        for (int n = 0; n < 4; ++n) {
            int gr0 = rowBase + wm * 64 + m * 16 + lg * 4;
            int gc = colBase + wn * 64 + n * 16 + l16;
            float bv = HAS_BIAS ? bias[gc] : 0.f;
#pragma unroll
            for (int r = 0; r < 4; ++r) {
                float v = acc[m][n][r] + bv;
                if (ACT_GELU) v = gelu_fn(v);
                if (HAS_RES) v += res[(size_t)(gr0 + r) * N + gc];
                if (OUT_BF16)
                    ((u16*)Cout)[(size_t)(gr0 + r) * N + gc] = f2bf(v);
                else
                    ((float*)Cout)[(size_t)(gr0 + r) * N + gc] = v;
            }
        }
    }
}

// ---------------- GEMM 256x256, BK=64, 8 waves, phase-pipelined ------------
// ROWCHUNK: XCD-chunk axis (R15-proven: row-chunk when A is the big operand).
// COARSE=0: R8-proven 8-phase (16 MFMA/phase). COARSE=1: 4-phase — same
// ds_read∥stage∥MFMA interleave and identical vmcnt ledger, but 32 MFMA per
// barrier pair (halves barrier+lgkm overhead; for short-K shapes like
// FFN-up's 8-iteration loop where barrier cost dominates).
template <int OUT_BF16, int HAS_BIAS, int ACT_GELU, int ROWCHUNK, int COARSE>
__global__ __launch_bounds__(512, 2) void gemm8p_kernel(
    const u16* __restrict__ A, const u16* __restrict__ Bt,
    const float* __restrict__ bias, void* __restrict__ Cout,
    int M, int N, int K, int ldk, int rowTiles, int koff, size_t coff)
{
    __shared__ u16 As[2][256 * 64];
    __shared__ u16 Bs[2][256 * 64];
    const int tid = threadIdx.x;
    const int lane = tid & 63, wave = tid >> 6;
    const int wm = wave >> 2, wn = wave & 3;     // 2 x 4 wave grid
    const int l16 = lane & 15, lg = lane >> 4;

    const int gx = gridDim.x, gy = gridDim.y;
    const int nwg = gx * gy;
    const int orig = (int)blockIdx.y * gx + (int)blockIdx.x;
    const int work = (orig & 7) * (nwg >> 3) + (orig >> 3);
    int colSel, wy;
    if (ROWCHUNK) { colSel = work % gx; wy = work / gx; }
    else          { colSel = work / gy; wy = work % gy; }
    const int colBase = colSel * 256;
    const int rowBase = (wy % rowTiles) * 256;
    const int ks = wy / rowTiles;
    A += (size_t)ks * koff;
    Bt += (size_t)ks * koff;

    f32x4 acc[8][4];
#pragma unroll
    for (int m = 0; m < 8; ++m)
#pragma unroll
        for (int n = 0; n < 4; ++n) acc[m][n] = (f32x4){0.f, 0.f, 0.f, 0.f};

#define STRIP(SB, KT, S)                                                      \
    {                                                                         \
        int tl_ = tid & 255, hf_ = tid >> 8;                                  \
        int r_ = hf_ * 128 + (S) * 32 + (tl_ >> 3);                           \
        int gl_ = (tl_ & 7) ^ (r_ & 7);                                       \
        int dst_ = r_ * 64 + (tl_ & 7) * 8;                                   \
        async_cp16(A + (size_t)(rowBase + r_) * ldk + (KT) + gl_ * 8, As[SB] + dst_); \
        async_cp16(Bt + (size_t)(colBase + r_) * ldk + (KT) + gl_ * 8, Bs[SB] + dst_); \
    }
#define FRAG_OFF(row, G) ((row) * 64 + (((G) ^ ((row) & 7)) * 8))

#define PHASE(BUF, QUAD, LOADB, STAGE, WAITN)                                 \
    {                                                                         \
        __builtin_amdgcn_sched_barrier(0);                                    \
        if (LOADB) {                                                          \
            _Pragma("unroll")                                                 \
            for (int nf = 0; nf < 4; ++nf) {                                  \
                int row = wn * 64 + nf * 16 + l16;                            \
                _Pragma("unroll")                                             \
                for (int ks_ = 0; ks_ < 2; ++ks_)                             \
                    bfr[nf][ks_] = *(const bf16x8*)(Bs[BUF] + FRAG_OFF(row, lg + ks_ * 4)); \
            }                                                                 \
        }                                                                     \
        bf16x8 af[2][2];                                                      \
        _Pragma("unroll")                                                     \
        for (int mi = 0; mi < 2; ++mi) {                                      \
            int row = wm * 128 + (QUAD) * 32 + mi * 16 + l16;                 \
            _Pragma("unroll")                                                 \
            for (int ks_ = 0; ks_ < 2; ++ks_)                                 \
                af[mi][ks_] = *(const bf16x8*)(As[BUF] + FRAG_OFF(row, lg + ks_ * 4)); \
        }                                                                     \
        STAGE;                                                                \
        __builtin_amdgcn_sched_barrier(0);                                    \
        __builtin_amdgcn_s_barrier();                                         \
        __builtin_amdgcn_s_setprio(1);                                        \
        _Pragma("unroll")                                                     \
        for (int mi = 0; mi < 2; ++mi)                                        \
            _Pragma("unroll")                                                 \
            for (int nf = 0; nf < 4; ++nf)                                    \
                _Pragma("unroll")                                             \
                for (int ks_ = 0; ks_ < 2; ++ks_)                             \
                    acc[(QUAD) * 2 + mi][nf] =                                \
                        __builtin_amdgcn_mfma_f32_16x16x32_bf16(              \
                            af[mi][ks_], bfr[nf][ks_], acc[(QUAD) * 2 + mi][nf], 0, 0, 0); \
        __builtin_amdgcn_s_setprio(0);                                        \
        __builtin_amdgcn_sched_barrier(0);                                    \
        WAITN;                                                                \
        __builtin_amdgcn_s_barrier();                                         \
    }

// 4-phase variant: two quadrants (Q0, Q0+1) per barrier pair, 32 MFMA.
#define PHASE2(BUF, Q0, LOADB, STAGE, WAITN)                                  \
    {                                                                         \
        __builtin_amdgcn_sched_barrier(0);                                    \
        if (LOADB) {                                                          \
            _Pragma("unroll")                                                 \
            for (int nf = 0; nf < 4; ++nf) {                                  \
                int row = wn * 64 + nf * 16 + l16;                            \
                _Pragma("unroll")                                             \
                for (int ks_ = 0; ks_ < 2; ++ks_)                             \
                    bfr[nf][ks_] = *(const bf16x8*)(Bs[BUF] + FRAG_OFF(row, lg + ks_ * 4)); \
            }                                                                 \
        }                                                                     \
        bf16x8 af2[4][2];                                                     \
        _Pragma("unroll")                                                     \
        for (int mi = 0; mi < 4; ++mi) {                                      \
            int row = wm * 128 + (Q0) * 32 + mi * 16 + l16;                   \
            _Pragma("unroll")                                                 \
            for (int ks_ = 0; ks_ < 2; ++ks_)                                 \
                af2[mi][ks_] = *(const bf16x8*)(As[BUF] + FRAG_OFF(row, lg + ks_ * 4)); \
        }                                                                     \
        STAGE;                                                                \
        __builtin_amdgcn_sched_barrier(0);                                    \
        __builtin_amdgcn_s_barrier();                                         \
        __builtin_amdgcn_s_setprio(1);                                        \
        _Pragma("unroll")                                                     \
        for (int mi = 0; mi < 4; ++mi)                                        \
            _Pragma("unroll")                                                 \
            for (int nf = 0; nf < 4; ++nf)                                    \
                _Pragma("unroll")                                             \
                for (int ks_ = 0; ks_ < 2; ++ks_)                             \
                    acc[(Q0) * 2 + mi][nf] =                                  \
                        __builtin_amdgcn_mfma_f32_16x16x32_bf16(              \
                            af2[mi][ks_], bfr[nf][ks_], acc[(Q0) * 2 + mi][nf], 0, 0, 0); \
        __builtin_amdgcn_s_setprio(0);                                        \
        __builtin_amdgcn_sched_barrier(0);                                    \
        WAITN;                                                                \
        __builtin_amdgcn_s_barrier();                                         \
    }

    const int nt = K >> 6;
    const int half = nt >> 1;

    STRIP(0, 0, 0); STRIP(0, 0, 1); STRIP(0, 0, 2); STRIP(0, 0, 3);
    STRIP(1, 64, 0); STRIP(1, 64, 1); STRIP(1, 64, 2);
    wait_vm6();
    __builtin_amdgcn_s_barrier();
    __builtin_amdgcn_sched_barrier(0);

    for (int it = 0; it < half; ++it) {
        const int kt1 = (it * 2 + 1) << 6;
        const int kt2 = (it * 2 + 2) << 6;
        const int kt3 = (it * 2 + 3) << 6;
        const bool more = (it + 1 < half);
        bf16x8 bfr[4][2];
        if (COARSE) {
            // 4 phases, identical in-flight ledger to the 8-phase schedule:
            // steady state 6 loads in; +4/+4 -> vm6 drains tile t+1; +4/+4 ->
            // vm6 drains tile t+2's first buffer. Tail drains to 0.
            PHASE2(0, 0, 1,
                   { STRIP(1, kt1, 3); if (more) STRIP(0, kt2, 0); },
                   ((void)0));
            PHASE2(0, 2, 0,
                   { if (more) { STRIP(0, kt2, 1); STRIP(0, kt2, 2); } },
                   if (more) wait_vm6(); else wait_vm0());
            PHASE2(1, 0, 1,
                   { if (more) { STRIP(0, kt2, 3); STRIP(1, kt3, 0); } },
                   ((void)0));
            PHASE2(1, 2, 0,
                   { if (more) { STRIP(1, kt3, 1); STRIP(1, kt3, 2); } },
                   if (more) wait_vm6(); else wait_vm0());
        } else {
            PHASE(0, 0, 1, STRIP(1, kt1, 3), ((void)0));
            PHASE(0, 1, 0, if (more) STRIP(0, kt2, 0), ((void)0));
            PHASE(0, 2, 0, if (more) STRIP(0, kt2, 1), ((void)0));
            PHASE(0, 3, 0, if (more) STRIP(0, kt2, 2),
                  if (more) wait_vm6(); else wait_vm0());
            PHASE(1, 0, 1, if (more) STRIP(0, kt2, 3), ((void)0));
            PHASE(1, 1, 0, if (more) STRIP(1, kt3, 0), ((void)0));
            PHASE(1, 2, 0, if (more) STRIP(1, kt3, 1), ((void)0));
            PHASE(1, 3, 0, if (more) STRIP(1, kt3, 2),
                  if (more) wait_vm6(); else wait_vm0());
        }
    }
#undef STRIP
#undef FRAG_OFF
#undef PHASE
#undef PHASE2

#pragma unroll
    for (int mf = 0; mf < 8; ++mf) {
#pragma unroll
        for (int nf = 0; nf < 4; ++nf) {
            int gr0 = rowBase + wm * 128 + mf * 16 + lg * 4;
            int gc = colBase + wn * 64 + nf * 16 + l16;
            float bv = HAS_BIAS ? bias[gc] : 0.f;
#pragma unroll
            for (int r = 0; r < 4; ++r) {
                float v = acc[mf][nf][r] + bv;
                if (ACT_GELU) v = gelu_fn(v);
                if (OUT_BF16)
                    ((u16*)Cout)[(size_t)ks * coff + (size_t)(gr0 + r) * N + gc] = f2bf(v);
                else
                    ((float*)Cout)[(size_t)ks * coff + (size_t)(gr0 + r) * N + gc] = v;
            }
        }
    }
}

// ---------------- causal flash attention (R12-proven: balanced grid) -------
__global__ __launch_bounds__(512) void attn_kernel(
    const u16* __restrict__ QKV, u16* __restrict__ Z)
{
    __shared__ u16 Ks[2][64 * 64];
    __shared__ u16 Vt[2][64 * 64];
    __shared__ u16 Pl[8][32 * 64];

    const int bh = blockIdx.x;               // 0..63
    const int b = bh >> 4, h = bh & 15;
    const int g = blockIdx.y;                // 0..7
    const int qt = (g < 4) ? (7 - g) : (g - 4);  // complementary at stride 256
    const int tid = threadIdx.x;
    const int wave = tid >> 6, lane = tid & 63;
    const int l16 = lane & 15, lg = lane >> 4;

    const size_t baseQ = (size_t)b * 2048 * 3072 + (size_t)h * 64;
    const size_t baseK = baseQ + 1024;
    const size_t baseV = baseQ + 2048;

    const int q0w = qt * 256 + wave * 32;

    // Q fragments, pre-scaled by 1/sqrt(64)=0.125 (exact pow2)
    bf16x8 aq[2][2];
#pragma unroll
    for (int mq = 0; mq < 2; ++mq) {
        const u16* qp = QKV + baseQ + (size_t)(q0w + mq * 16 + l16) * 3072;
#pragma unroll
        for (int hf = 0; hf < 2; ++hf) {
            bf16x8 v = *(const bf16x8*)(qp + hf * 32 + lg * 8);
#pragma unroll
            for (int j = 0; j < 8; ++j) v[j] = (__bf16)((float)v[j] * 0.125f);
            aq[mq][hf] = v;
        }
    }

    f32x4 o[2][4];
    float lrow[2][4];
#pragma unroll
    for (int mq = 0; mq < 2; ++mq)
#pragma unroll
        for (int i = 0; i < 4; ++i) {
            o[mq][i] = (f32x4){0.f, 0.f, 0.f, 0.f};
            lrow[mq][i] = 0.f;
        }

    const int nch = 4 * qt + 4;

    // 512 threads: one cp16 each covers the 64x64 K tile (xor-swizzled rows)
#define STAGE_K(BUF, KB)                                                      \
    {                                                                         \
        int n = tid;                                                          \
        int r = n >> 3;                                                       \
        int lb = ((n & 7) * 16) ^ ((r & 7) << 4);                             \
        async_cp16(QKV + baseK + (size_t)((KB) + r) * 3072 + (lb >> 1),       \
                   Ks[BUF] + n * 8);                                          \
    }
    // wave w owns d rows w*8..w*8+7; lane = k (64 lanes)
#define LOAD_V(KB, V0)                                                        \
    {                                                                         \
        const u16* vp = QKV + baseV + (size_t)((KB) + lane) * 3072;           \
        V0 = *(const u16x8*)(vp + wave * 8);                                  \
    }
#define WRITE_V(BUF, V0)                                                      \
    {                                                                         \
        _Pragma("unroll")                                                     \
        for (int j = 0; j < 8; ++j) {                                         \
            int d = wave * 8 + j;                                             \
            int byt = (d * 128 + lane * 2) ^ ((d & 7) << 4);                  \
            Vt[BUF][byt >> 1] = V0[j];                                        \
        }                                                                     \
    }
#define SOFTMAX_BODY(DIAG)                                                    \
    _Pragma("unroll")                                                         \
    for (int mq = 0; mq < 2; ++mq) {                                          \
        _Pragma("unroll")                                                     \
        for (int r = 0; r < 4; ++r) {                                         \
            float sv0 = s[mq][0][r];                                          \
            float sv1 = s[mq][1][r];                                          \
            float sv2 = s[mq][2][r];                                          \
            float sv3 = s[mq][3][r];                                          \
            if (DIAG) {                                                       \
                const int q = q0w + mq * 16 + lg * 4 + r;                     \
                if (kbase + 0 + l16 > q)  sv0 = -1e30f;                       \
                if (kbase + 16 + l16 > q) sv1 = -1e30f;                       \
                if (kbase + 32 + l16 > q) sv2 = -1e30f;                       \
                if (kbase + 48 + l16 > q) sv3 = -1e30f;                       \
            }                                                                 \
            float p0 = __expf(sv0), p1 = __expf(sv1);                         \
            float p2 = __expf(sv2), p3 = __expf(sv3);                         \
            lrow[mq][r] += (p0 + p1) + (p2 + p3);                             \
            int rowm = mq * 16 + lg * 4 + r;                                  \
            int rb = rowm * 128, swz = (rowm & 7) << 4;                       \
            Pl[wave][(rb + ((0  + 2 * l16) ^ swz)) >> 1] = f2bf(p0);          \
            Pl[wave][(rb + ((32 + 2 * l16) ^ swz)) >> 1] = f2bf(p1);          \
            Pl[wave][(rb + ((64 + 2 * l16) ^ swz)) >> 1] = f2bf(p2);          \
            Pl[wave][(rb + ((96 + 2 * l16) ^ swz)) >> 1] = f2bf(p3);          \
        }                                                                     \
    }

    // ---- prologue: stage chunk 0 into buffer 0 ----
    {
        STAGE_K(0, 0);
        u16x8 v0;
        LOAD_V(0, v0);
        WRITE_V(0, v0);
    }
    __syncthreads();

    int cur = 0;
    for (int kc = 0; kc < nch; ++kc) {
        const int kbase = kc * 64;
        const int nxt = cur ^ 1;
        const bool more = (kc + 1 < nch);
        u16x8 nv0;
        if (more) {
            STAGE_K(nxt, kbase + 64);      // async global->LDS, drains at barrier
            LOAD_V(kbase + 64, nv0);       // global->reg, written post-compute
        }

        if (q0w + 31 >= kbase) {
            // ---- QK^T: S[32 q][64 k] ----
            f32x4 s[2][4];
#pragma unroll
            for (int mq = 0; mq < 2; ++mq)
#pragma unroll
                for (int t = 0; t < 4; ++t) s[mq][t] = (f32x4){0.f, 0.f, 0.f, 0.f};
            __builtin_amdgcn_s_setprio(1);
#pragma unroll
            for (int t = 0; t < 4; ++t) {
                int row = t * 16 + l16;
                int swz = (row & 7) << 4;
                bf16x8 bk0 = *(const bf16x8*)(Ks[cur] + ((row * 128 + ((16 * lg) ^ swz)) >> 1));
                bf16x8 bk1 = *(const bf16x8*)(Ks[cur] + ((row * 128 + ((64 + 16 * lg) ^ swz)) >> 1));
#pragma unroll
                for (int mq = 0; mq < 2; ++mq) {
                    s[mq][t] = __builtin_amdgcn_mfma_f32_16x16x32_bf16(aq[mq][0], bk0, s[mq][t], 0, 0, 0);
                    s[mq][t] = __builtin_amdgcn_mfma_f32_16x16x32_bf16(aq[mq][1], bk1, s[mq][t], 0, 0, 0);
                }
            }
            __builtin_amdgcn_s_setprio(0);

            // ---- max-free softmax + P -> LDS ----
            const bool diag = (kbase + 63 > q0w);
            if (diag) { SOFTMAX_BODY(1) } else { SOFTMAX_BODY(0) }

            // ---- PV: O[32 q][64 d] += P @ V ----
            bf16x8 bv[2][4];
#pragma unroll
            for (int kst = 0; kst < 2; ++kst)
#pragma unroll
                for (int ct = 0; ct < 4; ++ct) {
                    int d = ct * 16 + l16;
                    bv[kst][ct] = *(const bf16x8*)(Vt[cur] + ((d * 128 + ((64 * kst + 16 * lg) ^ ((d & 7) << 4))) >> 1));
                }
            __builtin_amdgcn_s_setprio(1);
#pragma unroll
            for (int mq = 0; mq < 2; ++mq) {
                int rowm = mq * 16 + l16;
                int swz = (rowm & 7) << 4;
                bf16x8 ap0 = *(const bf16x8*)(&Pl[wave][(rowm * 128 + ((16 * lg) ^ swz)) >> 1]);
                bf16x8 ap1 = *(const bf16x8*)(&Pl[wave][(rowm * 128 + ((64 + 16 * lg) ^ swz)) >> 1]);
#pragma unroll
                for (int ct = 0; ct < 4; ++ct) {
                    o[mq][ct] = __builtin_amdgcn_mfma_f32_16x16x32_bf16(ap0, bv[0][ct], o[mq][ct], 0, 0, 0);
                    o[mq][ct] = __builtin_amdgcn_mfma_f32_16x16x32_bf16(ap1, bv[1][ct], o[mq][ct], 0, 0, 0);
                }
            }
            __builtin_amdgcn_s_setprio(0);
        }

        if (more) { WRITE_V(nxt, nv0); }   // vmcnt wait lands here (late)
        __syncthreads();                    // drains own async K + V writes
        cur = nxt;
    }

    // ---- epilogue: reduce l across the 16 k-lanes, normalize, store ----
#pragma unroll
    for (int mq = 0; mq < 2; ++mq)
#pragma unroll
        for (int r = 0; r < 4; ++r) {
            float l = lrow[mq][r];
            l += __shfl_xor(l, 1);
            l += __shfl_xor(l, 2);
            l += __shfl_xor(l, 4);
            l += __shfl_xor(l, 8);
            float inv = 1.f / l;
            size_t zr = ((size_t)b * 2048 + q0w + mq * 16 + lg * 4 + r) * 1024 + h * 64;
#pragma unroll
            for (int ct = 0; ct < 4; ++ct)
                Z[zr + ct * 16 + l16] = f2bf(o[mq][ct][r] * inv);
        }
#undef STAGE_K
#undef LOAD_V
#undef WRITE_V
#undef SOFTMAX_BODY
}

// ---------------------------------------------------------------------------
extern "C" void kernel_launch(void* const* d_in, const int* in_sizes, int n_in,
                              void* d_out, int out_size, void* d_ws, size_t ws_size,
                              hipStream_t stream)
{
    const float* X  = (const float*)d_in[0];
    const float* Wq = (const float*)d_in[1];
    const float* Wk = (const float*)d_in[2];
    const float* Wv = (const float*)d_in[3];
    const float* Wo = (const float*)d_in[4];
    const float* bo = (const float*)d_in[5];
    const float* W1 = (const float*)d_in[6];
    const float* b1 = (const float*)d_in[7];
    const float* W2 = (const float*)d_in[8];
    const float* b2 = (const float*)d_in[9];
    const float* g1 = (const float*)d_in[10];
    const float* s1 = (const float*)d_in[11];
    const float* g2 = (const float*)d_in[12];
    const float* s2 = (const float*)d_in[13];
    float* out = (float*)d_out;

    uint8_t* ws = (uint8_t*)d_ws;
    const size_t MB = 1024 * 1024;
    u16* Wqkvt = (u16*)(ws + 0 * MB);   // [3072][1024] bf16 (Q,K,V stacked)
    u16* Wot   = (u16*)(ws + 6 * MB);   // [1024][1024]
    u16* W1t   = (u16*)(ws + 8 * MB);   // [4096][1024]
    u16* W2t   = (u16*)(ws + 16 * MB);  // [1024][4096]
    u16* Yb    = (u16*)(ws + 24 * MB);  // [8192][1024] LN1 out
    u16* QKVb  = (u16*)(ws + 40 * MB);  // [8192][3072]
    u16* Zb    = (u16*)(ws + 24 * MB);  // reuse Yb (dead after QKV gemm)
    u16* Y2b   = (u16*)(ws + 40 * MB);  // reuse QKVb (dead after attention)
    u16* Hb    = (u16*)(ws + 56 * MB);  // [8192][4096]
    u16* Pk    = (u16*)(ws + 24 * MB);  // split-K partials [2][8192][1024] bf16
                                        // (24-56 MB: Zb+Y2b, dead by step 8)

    // 1) weight prep (single fused launch, 12288 tiles)
    wtrans_all_kernel<<<12288, 256, 0, stream>>>(Wq, Wk, Wv, Wo, W1, W2,
                                                 Wqkvt, Wot, W1t, W2t);

    // 2) LN1
    ln_kernel<<<8192, 256, 0, stream>>>(X, g1, s1, Yb);

    // 3) fused QKV projection (128^2 kernel; 1536 blocks, balanced)
    gemm_kernel<1, 0, 0, 0><<<dim3(24, 64), 256, 0, stream>>>(Yb, Wqkvt, nullptr, nullptr, QKVb, 8192, 3072, 1024);

    // 4) attention (QBLK=256, 8 waves, CU-balanced grid 64x8)
    attn_kernel<<<dim3(64, 8), 512, 0, stream>>>(QKVb, Zb);

    // 5) Wo projection + bo + shortcut X -> X1 (fp32 in d_out)
    gemm_kernel<0, 1, 1, 0><<<dim3(8, 64), 256, 0, stream>>>(Zb, Wot, bo, X, out, 8192, 1024, 1024);

    // 6) LN2
    ln_kernel<<<8192, 256, 0, stream>>>(out, g2, s2, Y2b);

    // 7) FFN up + gelu (COARSE 4-phase: 32 MFMA/barrier-pair; short-K shape
    //    where barrier overhead dominated — A/B isolated to this dispatch)
    gemm8p_kernel<1, 1, 1, 1, 1><<<dim3(16, 32), 512, 0, stream>>>(
        Y2b, W1t, b1, Hb, 8192, 4096, 1024, 1024, 32, 0, 0);

    // 8) FFN down, split-K=2, 8-phase (R14-proven; 16-iteration loop is
    //    already well-amortized)
    gemm8p_kernel<1, 0, 0, 1, 0><<<dim3(4, 64), 512, 0, stream>>>(
        Hb, W2t, nullptr, Pk, 8192, 1024, 2048, 4096, 32, 2048, (size_t)8192 * 1024);

    // 8b) combine: out += P0 + P1 + b2 (in-place on d_out, element-wise)
    combine_kernel<<<8192, 256, 0, stream>>>(Pk, Pk + (size_t)8192 * 1024, b2, out);
}

// Round 18
// 374.852 us; speedup vs baseline: 1.1009x; 1.0023x over previous
//
#include <hip/hip_runtime.h>
#include <cstdint>
#include <cstddef>

#define DEV static __device__ __forceinline__

typedef __bf16 bf16x8 __attribute__((ext_vector_type(8)));
typedef float f32x4 __attribute__((ext_vector_type(4)));
typedef unsigned short u16x8 __attribute__((ext_vector_type(8)));
typedef unsigned short u16;

DEV u16 f2bf(float f) { __bf16 b = (__bf16)f; return __builtin_bit_cast(u16, b); }
DEV float bf2f(u16 u) { unsigned v = (unsigned)u << 16; return __builtin_bit_cast(float, v); }

DEV void async_cp16(const void* g, void* l) {
    __builtin_amdgcn_global_load_lds(
        (const __attribute__((address_space(1))) void*)g,
        (__attribute__((address_space(3))) void*)l, 16, 0, 0);
}

DEV void wait_vm6() { asm volatile("s_waitcnt vmcnt(6)" ::: "memory"); }
DEV void wait_vm4() { asm volatile("s_waitcnt vmcnt(4)" ::: "memory"); }
DEV void wait_vm0() { asm volatile("s_waitcnt vmcnt(0)" ::: "memory"); }

// gelu with module's custom 0.04715 constant; overflow-safe tanh
DEV float gelu_fn(float x) {
    const float c = 0.7978845608028654f; // sqrt(2/pi)
    float t = c * (x + 0.04715f * x * x * x);
    float e = __expf(2.f * t);
    float th = 1.f - 2.f / (e + 1.f); // tanh(t), safe at +-inf
    return 0.5f * x * (1.f + th);
}

// ------------- fused weight transpose+cast: all 6 weights, 1 launch --------
__global__ __launch_bounds__(256) void wtrans_all_kernel(
    const float* __restrict__ Wq, const float* __restrict__ Wk,
    const float* __restrict__ Wv, const float* __restrict__ Wo,
    const float* __restrict__ W1, const float* __restrict__ W2,
    u16* __restrict__ Wqkvt, u16* __restrict__ Wot,
    u16* __restrict__ W1t, u16* __restrict__ W2t)
{
    const int bid = blockIdx.x;
    const float* W;
    u16* Wt;
    int K, N, nx, loc;
    if (bid < 4096) {
        loc = bid & 1023;
        const int wsel = bid >> 10;
        W = (wsel == 0) ? Wq : (wsel == 1) ? Wk : (wsel == 2) ? Wv : Wo;
        Wt = (wsel == 3) ? Wot : (Wqkvt + (size_t)wsel * 1024 * 1024);
        K = 1024; N = 1024; nx = 32;
    } else if (bid < 8192) {
        loc = bid - 4096; W = W1; Wt = W1t; K = 1024; N = 4096; nx = 128;
    } else {
        loc = bid - 8192; W = W2; Wt = W2t; K = 4096; N = 1024; nx = 32;
    }
    const int n0 = (loc % nx) * 32, k0 = (loc / nx) * 32;

    __shared__ float t[32][33];
    const int tx = threadIdx.x & 31, ty = threadIdx.x >> 5; // 32 x 8
#pragma unroll
    for (int i = 0; i < 4; ++i)
        t[ty + i * 8][tx] = W[(size_t)(k0 + ty + i * 8) * N + n0 + tx];
    __syncthreads();
#pragma unroll
    for (int i = 0; i < 4; ++i)
        Wt[(size_t)(n0 + ty + i * 8) * K + k0 + tx] = f2bf(t[tx][ty + i * 8]);
}

// ---------------- LayerNorm: f32 [rows][1024] -> bf16 ----------------------
__global__ __launch_bounds__(256) void ln_kernel(
    const float* __restrict__ X, const float* __restrict__ g,
    const float* __restrict__ sh, u16* __restrict__ Y)
{
    int row = blockIdx.x;
    const float4* xr = (const float4*)(X + (size_t)row * 1024);
    float4 x = xr[threadIdx.x];
    float s = x.x + x.y + x.z + x.w;
    float ss = x.x * x.x + x.y * x.y + x.z * x.z + x.w * x.w;
#pragma unroll
    for (int off = 32; off >= 1; off >>= 1) {
        s += __shfl_xor(s, off);
        ss += __shfl_xor(ss, off);
    }
    __shared__ float ps[4], pss[4];
    int wave = threadIdx.x >> 6, lane = threadIdx.x & 63;
    if (lane == 0) { ps[wave] = s; pss[wave] = ss; }
    __syncthreads();
    s = ps[0] + ps[1] + ps[2] + ps[3];
    ss = pss[0] + pss[1] + pss[2] + pss[3];
    float mean = s * (1.f / 1024.f);
    float var = ss * (1.f / 1024.f) - mean * mean;
    float rstd = rsqrtf(var + 1e-5f);
    int c = threadIdx.x * 4;
    ushort4 o;
    o.x = f2bf((x.x - mean) * rstd * g[c + 0] + sh[c + 0]);
    o.y = f2bf((x.y - mean) * rstd * g[c + 1] + sh[c + 1]);
    o.z = f2bf((x.z - mean) * rstd * g[c + 2] + sh[c + 2]);
    o.w = f2bf((x.w - mean) * rstd * g[c + 3] + sh[c + 3]);
    ((ushort4*)(Y + (size_t)row * 1024))[threadIdx.x] = o;
}

// ---------------- FFN-down split-K combine: out += P0 + P1 + b2 ------------
__global__ __launch_bounds__(256) void combine_kernel(
    const u16* __restrict__ P0, const u16* __restrict__ P1,
    const float* __restrict__ b2, float* __restrict__ out)
{
    const size_t row = blockIdx.x;
    const int c = threadIdx.x * 4;
    const size_t off = row * 1024 + c;
    ushort4 a = *(const ushort4*)(P0 + off);
    ushort4 b = *(const ushort4*)(P1 + off);
    float4 o = *(float4*)(out + off);
    o.x += bf2f(a.x) + bf2f(b.x) + b2[c + 0];
    o.y += bf2f(a.y) + bf2f(b.y) + b2[c + 1];
    o.z += bf2f(a.z) + bf2f(b.z) + b2[c + 2];
    o.w += bf2f(a.w) + bf2f(b.w) + b2[c + 3];
    *(float4*)(out + off) = o;
}

// ---------------- GEMM 128x128 (R12-proven): C = A @ Bt^T ------------------
// BK=32, 4 waves, 3-deep staging + counted vmcnt(4), single raw barrier per
// K-step (never drains the prefetch pipeline to 0 mid-loop).
template <int OUT_BF16, int HAS_BIAS, int HAS_RES, int ACT_GELU>
__global__ __launch_bounds__(256) void gemm_kernel(
    const u16* __restrict__ A, const u16* __restrict__ Bt,
    const float* __restrict__ bias, const float* __restrict__ res,
    void* __restrict__ Cout, int M, int N, int K)
{
    __shared__ u16 As[3][128 * 32];
    __shared__ u16 Bs[3][128 * 32];
    const int tid = threadIdx.x;
    const int lane = tid & 63, wave = tid >> 6;
    const int wm = wave >> 1, wn = wave & 1;
    const int l16 = lane & 15, lg = lane >> 4;
    const int rowBase = blockIdx.y * 128;
    const int colBase = blockIdx.x * 128;

    f32x4 acc[4][4];
#pragma unroll
    for (int m = 0; m < 4; ++m)
#pragma unroll
        for (int n = 0; n < 4; ++n) acc[m][n] = (f32x4){0.f, 0.f, 0.f, 0.f};

#define GSTAGE(SB, KT)                                                        \
    {                                                                         \
        _Pragma("unroll")                                                     \
        for (int i_ = 0; i_ < 2; ++i_) {                                      \
            int eo = tid * 8 + i_ * 2048;                                     \
            int r_ = eo >> 5, c_ = eo & 31;                                   \
            async_cp16(A + (size_t)(rowBase + r_) * K + (KT) + c_, As[SB] + eo); \
            async_cp16(Bt + (size_t)(colBase + r_) * K + (KT) + c_, Bs[SB] + eo); \
        }                                                                     \
    }

    const int nt = K >> 5;
    GSTAGE(0, 0);
    GSTAGE(1, 32);
    wait_vm4();
    __builtin_amdgcn_s_barrier();
    __builtin_amdgcn_sched_barrier(0);

    int cur = 0, stg = 2;
    for (int t = 0; t < nt; ++t) {
        const bool more = (t + 2 < nt);
        if (more) GSTAGE(stg, (t + 2) * 32);

        bf16x8 af[4], bfr[4];
#pragma unroll
        for (int m = 0; m < 4; ++m)
            af[m] = *(const bf16x8*)(As[cur] + (wm * 64 + m * 16 + l16) * 32 + lg * 8);
#pragma unroll
        for (int n = 0; n < 4; ++n)
            bfr[n] = *(const bf16x8*)(Bs[cur] + (wn * 64 + n * 16 + l16) * 32 + lg * 8);
#pragma unroll
        for (int m = 0; m < 4; ++m)
#pragma unroll
            for (int n = 0; n < 4; ++n)
                acc[m][n] = __builtin_amdgcn_mfma_f32_16x16x32_bf16(
                    af[m], bfr[n], acc[m][n], 0, 0, 0);

        if (more) wait_vm4(); else wait_vm0();
        __builtin_amdgcn_s_barrier();
        __builtin_amdgcn_sched_barrier(0);
        cur = (cur == 2) ? 0 : cur + 1;
        stg = (stg == 2) ? 0 : stg + 1;
    }
#undef GSTAGE

#pragma unroll
    for (int m = 0; m < 4; ++m) {
#pragma unroll
        for (int n = 0; n < 4; ++n) {
            int gr0 = rowBase + wm * 64 + m * 16 + lg * 4;
            int gc = colBase + wn * 64 + n * 16 + l16;
            float bv = HAS_BIAS ? bias[gc] : 0.f;
#pragma unroll
            for (int r = 0; r < 4; ++r) {
                float v = acc[m][n][r] + bv;
                if (ACT_GELU) v = gelu_fn(v);
                if (HAS_RES) v += res[(size_t)(gr0 + r) * N + gc];
                if (OUT_BF16)
                    ((u16*)Cout)[(size_t)(gr0 + r) * N + gc] = f2bf(v);
                else
                    ((float*)Cout)[(size_t)(gr0 + r) * N + gc] = v;
            }
        }
    }
}

// ---------------- GEMM 256x256, BK=64, 8 waves, phase-pipelined ------------
// ROWCHUNK: XCD-chunk axis (R15-proven). COARSE=0: R8-proven 8-phase.
// COARSE=1: 4-phase — same ds_read∥stage∥MFMA interleave, identical vmcnt
// ledger, 32 MFMA per barrier pair (R16-proven).
template <int OUT_BF16, int HAS_BIAS, int ACT_GELU, int ROWCHUNK, int COARSE>
__global__ __launch_bounds__(512, 2) void gemm8p_kernel(
    const u16* __restrict__ A, const u16* __restrict__ Bt,
    const float* __restrict__ bias, void* __restrict__ Cout,
    int M, int N, int K, int ldk, int rowTiles, int koff, size_t coff)
{
    __shared__ u16 As[2][256 * 64];
    __shared__ u16 Bs[2][256 * 64];
    const int tid = threadIdx.x;
    const int lane = tid & 63, wave = tid >> 6;
    const int wm = wave >> 2, wn = wave & 3;     // 2 x 4 wave grid
    const int l16 = lane & 15, lg = lane >> 4;

    const int gx = gridDim.x, gy = gridDim.y;
    const int nwg = gx * gy;
    const int orig = (int)blockIdx.y * gx + (int)blockIdx.x;
    const int work = (orig & 7) * (nwg >> 3) + (orig >> 3);
    int colSel, wy;
    if (ROWCHUNK) { colSel = work % gx; wy = work / gx; }
    else          { colSel = work / gy; wy = work % gy; }
    const int colBase = colSel * 256;
    const int rowBase = (wy % rowTiles) * 256;
    const int ks = wy / rowTiles;
    A += (size_t)ks * koff;
    Bt += (size_t)ks * koff;

    f32x4 acc[8][4];
#pragma unroll
    for (int m = 0; m < 8; ++m)
#pragma unroll
        for (int n = 0; n < 4; ++n) acc[m][n] = (f32x4){0.f, 0.f, 0.f, 0.f};

#define STRIP(SB, KT, S)                                                      \
    {                                                                         \
        int tl_ = tid & 255, hf_ = tid >> 8;                                  \
        int r_ = hf_ * 128 + (S) * 32 + (tl_ >> 3);                           \
        int gl_ = (tl_ & 7) ^ (r_ & 7);                                       \
        int dst_ = r_ * 64 + (tl_ & 7) * 8;                                   \
        async_cp16(A + (size_t)(rowBase + r_) * ldk + (KT) + gl_ * 8, As[SB] + dst_); \
        async_cp16(Bt + (size_t)(colBase + r_) * ldk + (KT) + gl_ * 8, Bs[SB] + dst_); \
    }
#define FRAG_OFF(row, G) ((row) * 64 + (((G) ^ ((row) & 7)) * 8))

#define PHASE(BUF, QUAD, LOADB, STAGE, WAITN)                                 \
    {                                                                         \
        __builtin_amdgcn_sched_barrier(0);                                    \
        if (LOADB) {                                                          \
            _Pragma("unroll")                                                 \
            for (int nf = 0; nf < 4; ++nf) {                                  \
                int row = wn * 64 + nf * 16 + l16;                            \
                _Pragma("unroll")                                             \
                for (int ks_ = 0; ks_ < 2; ++ks_)                             \
                    bfr[nf][ks_] = *(const bf16x8*)(Bs[BUF] + FRAG_OFF(row, lg + ks_ * 4)); \
            }                                                                 \
        }                                                                     \
        bf16x8 af[2][2];                                                      \
        _Pragma("unroll")                                                     \
        for (int mi = 0; mi < 2; ++mi) {                                      \
            int row = wm * 128 + (QUAD) * 32 + mi * 16 + l16;                 \
            _Pragma("unroll")                                                 \
            for (int ks_ = 0; ks_ < 2; ++ks_)                                 \
                af[mi][ks_] = *(const bf16x8*)(As[BUF] + FRAG_OFF(row, lg + ks_ * 4)); \
        }                                                                     \
        STAGE;                                                                \
        __builtin_amdgcn_sched_barrier(0);                                    \
        __builtin_amdgcn_s_barrier();                                         \
        __builtin_amdgcn_s_setprio(1);                                        \
        _Pragma("unroll")                                                     \
        for (int mi = 0; mi < 2; ++mi)                                        \
            _Pragma("unroll")                                                 \
            for (int nf = 0; nf < 4; ++nf)                                    \
                _Pragma("unroll")                                             \
                for (int ks_ = 0; ks_ < 2; ++ks_)                             \
                    acc[(QUAD) * 2 + mi][nf] =                                \
                        __builtin_amdgcn_mfma_f32_16x16x32_bf16(              \
                            af[mi][ks_], bfr[nf][ks_], acc[(QUAD) * 2 + mi][nf], 0, 0, 0); \
        __builtin_amdgcn_s_setprio(0);                                        \
        __builtin_amdgcn_sched_barrier(0);                                    \
        WAITN;                                                                \
        __builtin_amdgcn_s_barrier();                                         \
    }

// 4-phase variant: two quadrants (Q0, Q0+1) per barrier pair, 32 MFMA.
#define PHASE2(BUF, Q0, LOADB, STAGE, WAITN)                                  \
    {                                                                         \
        __builtin_amdgcn_sched_barrier(0);                                    \
        if (LOADB) {                                                          \
            _Pragma("unroll")                                                 \
            for (int nf = 0; nf < 4; ++nf) {                                  \
                int row = wn * 64 + nf * 16 + l16;                            \
                _Pragma("unroll")                                             \
                for (int ks_ = 0; ks_ < 2; ++ks_)                             \
                    bfr[nf][ks_] = *(const bf16x8*)(Bs[BUF] + FRAG_OFF(row, lg + ks_ * 4)); \
            }                                                                 \
        }                                                                     \
        bf16x8 af2[4][2];                                                     \
        _Pragma("unroll")                                                     \
        for (int mi = 0; mi < 4; ++mi) {                                      \
            int row = wm * 128 + (Q0) * 32 + mi * 16 + l16;                   \
            _Pragma("unroll")                                                 \
            for (int ks_ = 0; ks_ < 2; ++ks_)                                 \
                af2[mi][ks_] = *(const bf16x8*)(As[BUF] + FRAG_OFF(row, lg + ks_ * 4)); \
        }                                                                     \
        STAGE;                                                                \
        __builtin_amdgcn_sched_barrier(0);                                    \
        __builtin_amdgcn_s_barrier();                                         \
        __builtin_amdgcn_s_setprio(1);                                        \
        _Pragma("unroll")                                                     \
        for (int mi = 0; mi < 4; ++mi)                                        \
            _Pragma("unroll")                                                 \
            for (int nf = 0; nf < 4; ++nf)                                    \
                _Pragma("unroll")                                             \
                for (int ks_ = 0; ks_ < 2; ++ks_)                             \
                    acc[(Q0) * 2 + mi][nf] =                                  \
                        __builtin_amdgcn_mfma_f32_16x16x32_bf16(              \
                            af2[mi][ks_], bfr[nf][ks_], acc[(Q0) * 2 + mi][nf], 0, 0, 0); \
        __builtin_amdgcn_s_setprio(0);                                        \
        __builtin_amdgcn_sched_barrier(0);                                    \
        WAITN;                                                                \
        __builtin_amdgcn_s_barrier();                                         \
    }

    const int nt = K >> 6;
    const int half = nt >> 1;

    STRIP(0, 0, 0); STRIP(0, 0, 1); STRIP(0, 0, 2); STRIP(0, 0, 3);
    STRIP(1, 64, 0); STRIP(1, 64, 1); STRIP(1, 64, 2);
    wait_vm6();
    __builtin_amdgcn_s_barrier();
    __builtin_amdgcn_sched_barrier(0);

    for (int it = 0; it < half; ++it) {
        const int kt1 = (it * 2 + 1) << 6;
        const int kt2 = (it * 2 + 2) << 6;
        const int kt3 = (it * 2 + 3) << 6;
        const bool more = (it + 1 < half);
        bf16x8 bfr[4][2];
        if (COARSE) {
            // 4 phases, identical in-flight ledger to the 8-phase schedule:
            // steady state 6 loads in; +4/+4 -> vm6 drains tile t+1; +4/+4 ->
            // vm6 drains tile t+2's first buffer. Tail drains to 0.
            PHASE2(0, 0, 1,
                   { STRIP(1, kt1, 3); if (more) STRIP(0, kt2, 0); },
                   ((void)0));
            PHASE2(0, 2, 0,
                   { if (more) { STRIP(0, kt2, 1); STRIP(0, kt2, 2); } },
                   if (more) wait_vm6(); else wait_vm0());
            PHASE2(1, 0, 1,
                   { if (more) { STRIP(0, kt2, 3); STRIP(1, kt3, 0); } },
                   ((void)0));
            PHASE2(1, 2, 0,
                   { if (more) { STRIP(1, kt3, 1); STRIP(1, kt3, 2); } },
                   if (more) wait_vm6(); else wait_vm0());
        } else {
            PHASE(0, 0, 1, STRIP(1, kt1, 3), ((void)0));
            PHASE(0, 1, 0, if (more) STRIP(0, kt2, 0), ((void)0));
            PHASE(0, 2, 0, if (more) STRIP(0, kt2, 1), ((void)0));
            PHASE(0, 3, 0, if (more) STRIP(0, kt2, 2),
                  if (more) wait_vm6(); else wait_vm0());
            PHASE(1, 0, 1, if (more) STRIP(0, kt2, 3), ((void)0));
            PHASE(1, 1, 0, if (more) STRIP(1, kt3, 0), ((void)0));
            PHASE(1, 2, 0, if (more) STRIP(1, kt3, 1), ((void)0));
            PHASE(1, 3, 0, if (more) STRIP(1, kt3, 2),
                  if (more) wait_vm6(); else wait_vm0());
        }
    }
#undef STRIP
#undef FRAG_OFF
#undef PHASE
#undef PHASE2

#pragma unroll
    for (int mf = 0; mf < 8; ++mf) {
#pragma unroll
        for (int nf = 0; nf < 4; ++nf) {
            int gr0 = rowBase + wm * 128 + mf * 16 + lg * 4;
            int gc = colBase + wn * 64 + nf * 16 + l16;
            float bv = HAS_BIAS ? bias[gc] : 0.f;
#pragma unroll
            for (int r = 0; r < 4; ++r) {
                float v = acc[mf][nf][r] + bv;
                if (ACT_GELU) v = gelu_fn(v);
                if (OUT_BF16)
                    ((u16*)Cout)[(size_t)ks * coff + (size_t)(gr0 + r) * N + gc] = f2bf(v);
                else
                    ((float*)Cout)[(size_t)ks * coff + (size_t)(gr0 + r) * N + gc] = v;
            }
        }
    }
}

// ---------------- causal flash attention (R12-proven: balanced grid) -------
__global__ __launch_bounds__(512) void attn_kernel(
    const u16* __restrict__ QKV, u16* __restrict__ Z)
{
    __shared__ u16 Ks[2][64 * 64];
    __shared__ u16 Vt[2][64 * 64];
    __shared__ u16 Pl[8][32 * 64];

    const int bh = blockIdx.x;               // 0..63
    const int b = bh >> 4, h = bh & 15;
    const int g = blockIdx.y;                // 0..7
    const int qt = (g < 4) ? (7 - g) : (g - 4);  // complementary at stride 256
    const int tid = threadIdx.x;
    const int wave = tid >> 6, lane = tid & 63;
    const int l16 = lane & 15, lg = lane >> 4;

    const size_t baseQ = (size_t)b * 2048 * 3072 + (size_t)h * 64;
    const size_t baseK = baseQ + 1024;
    const size_t baseV = baseQ + 2048;

    const int q0w = qt * 256 + wave * 32;

    // Q fragments, pre-scaled by 1/sqrt(64)=0.125 (exact pow2)
    bf16x8 aq[2][2];
#pragma unroll
    for (int mq = 0; mq < 2; ++mq) {
        const u16* qp = QKV + baseQ + (size_t)(q0w + mq * 16 + l16) * 3072;
#pragma unroll
        for (int hf = 0; hf < 2; ++hf) {
            bf16x8 v = *(const bf16x8*)(qp + hf * 32 + lg * 8);
#pragma unroll
            for (int j = 0; j < 8; ++j) v[j] = (__bf16)((float)v[j] * 0.125f);
            aq[mq][hf] = v;
        }
    }

    f32x4 o[2][4];
    float lrow[2][4];
#pragma unroll
    for (int mq = 0; mq < 2; ++mq)
#pragma unroll
        for (int i = 0; i < 4; ++i) {
            o[mq][i] = (f32x4){0.f, 0.f, 0.f, 0.f};
            lrow[mq][i] = 0.f;
        }

    const int nch = 4 * qt + 4;

    // 512 threads: one cp16 each covers the 64x64 K tile (xor-swizzled rows)
#define STAGE_K(BUF, KB)                                                      \
    {                                                                         \
        int n = tid;                                                          \
        int r = n >> 3;                                                       \
        int lb = ((n & 7) * 16) ^ ((r & 7) << 4);                             \
        async_cp16(QKV + baseK + (size_t)((KB) + r) * 3072 + (lb >> 1),       \
                   Ks[BUF] + n * 8);                                          \
    }
    // wave w owns d rows w*8..w*8+7; lane = k (64 lanes)
#define LOAD_V(KB, V0)                                                        \
    {                                                                         \
        const u16* vp = QKV + baseV + (size_t)((KB) + lane) * 3072;           \
        V0 = *(const u16x8*)(vp + wave * 8);                                  \
    }
#define WRITE_V(BUF, V0)                                                      \
    {                                                                         \
        _Pragma("unroll")                                                     \
        for (int j = 0; j < 8; ++j) {                                         \
            int d = wave * 8 + j;                                             \
            int byt = (d * 128 + lane * 2) ^ ((d & 7) << 4);                  \
            Vt[BUF][byt >> 1] = V0[j];                                        \
        }                                                                     \
    }
#define SOFTMAX_BODY(DIAG)                                                    \
    _Pragma("unroll")                                                         \
    for (int mq = 0; mq < 2; ++mq) {                                          \
        _Pragma("unroll")                                                     \
        for (int r = 0; r < 4; ++r) {                                         \
            float sv0 = s[mq][0][r];                                          \
            float sv1 = s[mq][1][r];                                          \
            float sv2 = s[mq][2][r];                                          \
            float sv3 = s[mq][3][r];                                          \
            if (DIAG) {                                                       \
                const int q = q0w + mq * 16 + lg * 4 + r;                     \
                if (kbase + 0 + l16 > q)  sv0 = -1e30f;                       \
                if (kbase + 16 + l16 > q) sv1 = -1e30f;                       \
                if (kbase + 32 + l16 > q) sv2 = -1e30f;                       \
                if (kbase + 48 + l16 > q) sv3 = -1e30f;                       \
            }                                                                 \
            float p0 = __expf(sv0), p1 = __expf(sv1);                         \
            float p2 = __expf(sv2), p3 = __expf(sv3);                         \
            lrow[mq][r] += (p0 + p1) + (p2 + p3);                             \
            int rowm = mq * 16 + lg * 4 + r;                                  \
            int rb = rowm * 128, swz = (rowm & 7) << 4;                       \
            Pl[wave][(rb + ((0  + 2 * l16) ^ swz)) >> 1] = f2bf(p0);          \
            Pl[wave][(rb + ((32 + 2 * l16) ^ swz)) >> 1] = f2bf(p1);          \
            Pl[wave][(rb + ((64 + 2 * l16) ^ swz)) >> 1] = f2bf(p2);          \
            Pl[wave][(rb + ((96 + 2 * l16) ^ swz)) >> 1] = f2bf(p3);          \
        }                                                                     \
    }

    // ---- prologue: stage chunk 0 into buffer 0 ----
    {
        STAGE_K(0, 0);
        u16x8 v0;
        LOAD_V(0, v0);
        WRITE_V(0, v0);
    }
    __syncthreads();

    int cur = 0;
    for (int kc = 0; kc < nch; ++kc) {
        const int kbase = kc * 64;
        const int nxt = cur ^ 1;
        const bool more = (kc + 1 < nch);
        u16x8 nv0;
        if (more) {
            STAGE_K(nxt, kbase + 64);      // async global->LDS, drains at barrier
            LOAD_V(kbase + 64, nv0);       // global->reg, written post-compute
        }

        if (q0w + 31 >= kbase) {
            // ---- QK^T: S[32 q][64 k] ----
            f32x4 s[2][4];
#pragma unroll
            for (int mq = 0; mq < 2; ++mq)
#pragma unroll
                for (int t = 0; t < 4; ++t) s[mq][t] = (f32x4){0.f, 0.f, 0.f, 0.f};
            __builtin_amdgcn_s_setprio(1);
#pragma unroll
            for (int t = 0; t < 4; ++t) {
                int row = t * 16 + l16;
                int swz = (row & 7) << 4;
                bf16x8 bk0 = *(const bf16x8*)(Ks[cur] + ((row * 128 + ((16 * lg) ^ swz)) >> 1));
                bf16x8 bk1 = *(const bf16x8*)(Ks[cur] + ((row * 128 + ((64 + 16 * lg) ^ swz)) >> 1));
#pragma unroll
                for (int mq = 0; mq < 2; ++mq) {
                    s[mq][t] = __builtin_amdgcn_mfma_f32_16x16x32_bf16(aq[mq][0], bk0, s[mq][t], 0, 0, 0);
                    s[mq][t] = __builtin_amdgcn_mfma_f32_16x16x32_bf16(aq[mq][1], bk1, s[mq][t], 0, 0, 0);
                }
            }
            __builtin_amdgcn_s_setprio(0);

            // ---- max-free softmax + P -> LDS ----
            const bool diag = (kbase + 63 > q0w);
            if (diag) { SOFTMAX_BODY(1) } else { SOFTMAX_BODY(0) }

            // ---- PV: O[32 q][64 d] += P @ V ----
            bf16x8 bv[2][4];
#pragma unroll
            for (int kst = 0; kst < 2; ++kst)
#pragma unroll
                for (int ct = 0; ct < 4; ++ct) {
                    int d = ct * 16 + l16;
                    bv[kst][ct] = *(const bf16x8*)(Vt[cur] + ((d * 128 + ((64 * kst + 16 * lg) ^ ((d & 7) << 4))) >> 1));
                }
            __builtin_amdgcn_s_setprio(1);
#pragma unroll
            for (int mq = 0; mq < 2; ++mq) {
                int rowm = mq * 16 + l16;
                int swz = (rowm & 7) << 4;
                bf16x8 ap0 = *(const bf16x8*)(&Pl[wave][(rowm * 128 + ((16 * lg) ^ swz)) >> 1]);
                bf16x8 ap1 = *(const bf16x8*)(&Pl[wave][(rowm * 128 + ((64 + 16 * lg) ^ swz)) >> 1]);
#pragma unroll
                for (int ct = 0; ct < 4; ++ct) {
                    o[mq][ct] = __builtin_amdgcn_mfma_f32_16x16x32_bf16(ap0, bv[0][ct], o[mq][ct], 0, 0, 0);
                    o[mq][ct] = __builtin_amdgcn_mfma_f32_16x16x32_bf16(ap1, bv[1][ct], o[mq][ct], 0, 0, 0);
                }
            }
            __builtin_amdgcn_s_setprio(0);
        }

        if (more) { WRITE_V(nxt, nv0); }   // vmcnt wait lands here (late)
        __syncthreads();                    // drains own async K + V writes
        cur = nxt;
    }

    // ---- epilogue: reduce l across the 16 k-lanes, normalize, store ----
#pragma unroll
    for (int mq = 0; mq < 2; ++mq)
#pragma unroll
        for (int r = 0; r < 4; ++r) {
            float l = lrow[mq][r];
            l += __shfl_xor(l, 1);
            l += __shfl_xor(l, 2);
            l += __shfl_xor(l, 4);
            l += __shfl_xor(l, 8);
            float inv = 1.f / l;
            size_t zr = ((size_t)b * 2048 + q0w + mq * 16 + lg * 4 + r) * 1024 + h * 64;
#pragma unroll
            for (int ct = 0; ct < 4; ++ct)
                Z[zr + ct * 16 + l16] = f2bf(o[mq][ct][r] * inv);
        }
#undef STAGE_K
#undef LOAD_V
#undef WRITE_V
#undef SOFTMAX_BODY
}

// ---------------------------------------------------------------------------
extern "C" void kernel_launch(void* const* d_in, const int* in_sizes, int n_in,
                              void* d_out, int out_size, void* d_ws, size_t ws_size,
                              hipStream_t stream)
{
    const float* X  = (const float*)d_in[0];
    const float* Wq = (const float*)d_in[1];
    const float* Wk = (const float*)d_in[2];
    const float* Wv = (const float*)d_in[3];
    const float* Wo = (const float*)d_in[4];
    const float* bo = (const float*)d_in[5];
    const float* W1 = (const float*)d_in[6];
    const float* b1 = (const float*)d_in[7];
    const float* W2 = (const float*)d_in[8];
    const float* b2 = (const float*)d_in[9];
    const float* g1 = (const float*)d_in[10];
    const float* s1 = (const float*)d_in[11];
    const float* g2 = (const float*)d_in[12];
    const float* s2 = (const float*)d_in[13];
    float* out = (float*)d_out;

    uint8_t* ws = (uint8_t*)d_ws;
    const size_t MB = 1024 * 1024;
    u16* Wqkvt = (u16*)(ws + 0 * MB);   // [3072][1024] bf16 (Q,K,V stacked)
    u16* Wot   = (u16*)(ws + 6 * MB);   // [1024][1024]
    u16* W1t   = (u16*)(ws + 8 * MB);   // [4096][1024]
    u16* W2t   = (u16*)(ws + 16 * MB);  // [1024][4096]
    u16* Yb    = (u16*)(ws + 24 * MB);  // [8192][1024] LN1 out
    u16* QKVb  = (u16*)(ws + 40 * MB);  // [8192][3072]
    u16* Zb    = (u16*)(ws + 24 * MB);  // reuse Yb (dead after QKV gemm)
    u16* Y2b   = (u16*)(ws + 40 * MB);  // reuse QKVb (dead after attention)
    u16* Hb    = (u16*)(ws + 56 * MB);  // [8192][4096]
    u16* Pk    = (u16*)(ws + 24 * MB);  // split-K partials [2][8192][1024] bf16
                                        // (24-56 MB: Zb+Y2b, dead by step 8)

    // 1) weight prep (single fused launch, 12288 tiles)
    wtrans_all_kernel<<<12288, 256, 0, stream>>>(Wq, Wk, Wv, Wo, W1, W2,
                                                 Wqkvt, Wot, W1t, W2t);

    // 2) LN1
    ln_kernel<<<8192, 256, 0, stream>>>(X, g1, s1, Yb);

    // 3) fused QKV projection (128^2 kernel; 1536 blocks, balanced)
    gemm_kernel<1, 0, 0, 0><<<dim3(24, 64), 256, 0, stream>>>(Yb, Wqkvt, nullptr, nullptr, QKVb, 8192, 3072, 1024);

    // 4) attention (QBLK=256, 8 waves, CU-balanced grid 64x8)
    attn_kernel<<<dim3(64, 8), 512, 0, stream>>>(QKVb, Zb);

    // 5) Wo projection + bo + shortcut X -> X1 (fp32 in d_out)
    gemm_kernel<0, 1, 1, 0><<<dim3(8, 64), 256, 0, stream>>>(Zb, Wot, bo, X, out, 8192, 1024, 1024);

    // 6) LN2
    ln_kernel<<<8192, 256, 0, stream>>>(out, g2, s2, Y2b);

    // 7) FFN up + gelu (R16-proven: COARSE 4-phase, grid 16x32)
    gemm8p_kernel<1, 1, 1, 1, 1><<<dim3(16, 32), 512, 0, stream>>>(
        Y2b, W1t, b1, Hb, 8192, 4096, 1024, 1024, 32, 0, 0);

    // 8) FFN down, split-K=2, 8-phase (R14-proven)
    gemm8p_kernel<1, 0, 0, 1, 0><<<dim3(4, 64), 512, 0, stream>>>(
        Hb, W2t, nullptr, Pk, 8192, 1024, 2048, 4096, 32, 2048, (size_t)8192 * 1024);

    // 8b) combine: out += P0 + P1 + b2 (in-place on d_out, element-wise)
    combine_kernel<<<8192, 256, 0, stream>>>(Pk, Pk + (size_t)8192 * 1024, b2, out);
}